// Round 19
// baseline (132.891 us; speedup 1.0000x reference)
//
#include <hip/hip_runtime.h>
#include <math.h>

#define B 16
#define NAV 36
#define HIM 120
#define WIM 160
#define RH 512
#define NF 4
#define AE 37

// ---------------- workspace layout (floats) ----------------
// attn   : [B*NAV]            @ 0        (576)
// dfa    : [B*NF]             @ 576      (64)
// y1     : [2][B][64][269]    @ 1792     (550912)
// cpano  : [B][72][1920]      @ 552704   (2211840)
// wsC    : [576][240]         @ 2764544  (138240)

// ============ kernel 1: fused head (attn softmax + MLP) + weight compose ============
// One block per (b,i). Each block recomputes b's attn softmax and dfa MLP
// locally (65k MAC over 192 threads - trivial); i==0 blocks publish attn row
// and dfa for k_fix / k_lstm. Then composes C9 = kd (*) W1 as before.
__global__ __launch_bounds__(192) void k_comp(
    const float* __restrict__ nnf, const float* __restrict__ ctx,
    const float* __restrict__ fc1w, const float* __restrict__ fc1b,
    const float* __restrict__ fc2w, const float* __restrict__ fc2b,
    const float* __restrict__ c1w, const float* __restrict__ c1b,
    const float* __restrict__ dynf,
    float* __restrict__ attn, float* __restrict__ dfa,
    float* __restrict__ wsC) {
  int bi = blockIdx.x;
  int b = bi / NAV, i = bi - b * NAV;
  int t = threadIdx.x;
  __shared__ float s_ctx[RH];
  __shared__ float s_hid[128];
  __shared__ float s_dfa[NF];
  __shared__ float s_attn;
  __shared__ float s_kd[50];
  __shared__ float s_w1[50];

  for (int k = t; k < RH; k += 192) s_ctx[k] = ctx[b * RH + k];
  __syncthreads();
  if (t < 128) {
    float acc = fc1b[t];
    const float* wr = fc1w + t * RH;
    for (int k = 0; k < RH; k++) acc += s_ctx[k] * wr[k];
    s_hid[t] = fmaxf(acc, 0.0f);
  } else if (t == 190) {
    // attn softmax for this (b,i): needs all 36 nnf values of b
    const float* nb = nnf + b * NAV;
    float m = -1e30f;
    for (int k2 = 0; k2 < NAV; k2++) m = fmaxf(m, nb[k2]);
    float s = 0.f, mine = 0.f;
    for (int k2 = 0; k2 < NAV; k2++) {
      float e = expf(nb[k2] - m);
      s += e;
      if (k2 == i) mine = e;
    }
    s_attn = mine / s;
  }
  __syncthreads();
  if (t < NF) {
    float a = fc2b[t];
    const float* w2 = fc2w + t * 128;
    for (int k = 0; k < 128; k++) a += s_hid[k] * w2[k];
    s_dfa[t] = a;
  }
  __syncthreads();
  if (t == 0) {
    float m = fmaxf(fmaxf(s_dfa[0], s_dfa[1]), fmaxf(s_dfa[2], s_dfa[3]));
    float s = 0.f;
    for (int f = 0; f < NF; f++) { s_dfa[f] = expf(s_dfa[f] - m); s += s_dfa[f]; }
    float inv = 1.0f / s;
    for (int f = 0; f < NF; f++) s_dfa[f] *= inv;
  }
  __syncthreads();
  // publish attn (own entry) and dfa (i==0 blocks)
  if (t == 0) {
    attn[bi] = s_attn;
    if (i == 0) for (int f = 0; f < NF; f++) dfa[b * NF + f] = s_dfa[f];
  }
  if (t < 50) {
    float a = 0.f;
    for (int f = 0; f < NF; f++) a += s_dfa[f] * dynf[(f * NAV + i) * 50 + t];
    s_kd[t] = a;
    s_w1[t] = c1w[i * 50 + t];
  }
  __syncthreads();
  float attn_bi = s_attn;
  float* o = wsC + (size_t)bi * 240;
  if (t < 162) {
    int ch = t < 81 ? 0 : 1;
    int uv = t - 81 * ch;
    int u = uv / 9, v = uv - 9 * u;
    float c = 0.f;
    for (int a = 0; a < 5; a++) {
      int cc = u - a; if (cc < 0 || cc > 4) continue;
      for (int bb = 0; bb < 5; bb++) {
        int d = v - bb; if (d < 0 || d > 4) continue;
        c += s_kd[a * 5 + bb] * s_w1[ch * 25 + cc * 5 + d];
      }
    }
    o[ch * 81 + uv] = c * attn_bi;
  } else if (t < 187) {
    o[t] = s_kd[25 + (t - 162)] * attn_bi;   // attn*kd_po
  } else if (t == 187) {
    float s2 = 0.f;
    for (int j = 0; j < 25; j++) s2 += s_kd[j];
    o[187] = attn_bi * c1b[i] * s2;
  }
  if (t < 50) o[188 + t] = s_kd[t];
}

// ============ kernel 2: composed 9x9 conv -> compact pano (R18-best) ============
#define LDW 168
__global__ __launch_bounds__(512) void k_conv(
    const float* __restrict__ draw, const float* __restrict__ dclip,
    const float* __restrict__ obj,
    const float* __restrict__ wsC,
    float* __restrict__ cpano) {
  __shared__ __align__(16) float s_raw[24 * LDW];
  __shared__ __align__(16) float s_clip[24 * LDW];
  __shared__ __align__(16) float s_po[20 * LDW];
  __shared__ __align__(16) float s_part[1920];   // [part][160] float4
  __shared__ float s_C[188];

  int t = threadIdx.x;
  int bz = blockIdx.x;
  int half = bz & 1;
  int pi = bz >> 1;
  int b = pi / NAV, i = pi - b * NAV;
  int ybase = 60 * half;

  const size_t plane = (size_t)pi * HIM * WIM;
  const float* rawp = draw + plane;
  const float* clipp = dclip + plane;
  const float* objp = obj + plane;
  int q = i / 12, cw = i - 12 * q;
  float* cpb = cpano + ((size_t)b * 72 + (2 - q) * 24) * 1920 + cw * WIM;

  const float* cp = wsC + (size_t)pi * 240;
  if (t < 188) s_C[t] = cp[t];
  if (t < 384) {
    int ha = t < 192 ? 0 : 1, rem = t - 192 * ha;
    int r = rem >> 3, hc = rem & 7;
    int col = hc < 4 ? hc : 160 + hc;
    (ha ? s_clip : s_raw)[r * LDW + col] = 0.f;
  }
  if (t < 160) {
    int r = t >> 3, hc = t & 7;
    int col = hc < 4 ? hc : 160 + hc;
    s_po[r * LDW + col] = 0.f;
  }

  int prow[2], pg3[2]; bool pra[2];
#pragma unroll
  for (int jj = 0; jj < 2; jj++) {
    int idx = t + 512 * jj;
    pra[jj] = idx < 960;
    prow[jj] = idx / 40;
    pg3[jj] = idx - 40 * prow[jj];
  }
  int vrow[2], vg[2]; bool va[2];
#pragma unroll
  for (int jj = 0; jj < 2; jj++) {
    int idx = t + 512 * jj;
    va[jj] = idx < 800;
    vrow[jj] = idx / 40;
    vg[jj] = idx - 40 * vrow[jj];
  }
  int part = t / 160;
  int pgc = t - 160 * part;
  int row4 = pgc / 40;
  int gc = pgc - 40 * row4;
  int x0 = 4 * gc;
  int rbase = 5 * row4;
  bool cact = (t < 480);
  int rrow4 = t / 40;
  int rg = t - 40 * rrow4;

  for (int tt = 0; tt < 3; tt++) {
    int y0 = ybase + 20 * tt;
    {
      float4 vr[2], vc[2], vo[2];
#pragma unroll
      for (int jj = 0; jj < 2; jj++) {
        int gy = y0 - 4 + prow[jj];
        bool ok = pra[jj] && gy >= 0 && gy < HIM;
        float4 a = {0.f, 0.f, 0.f, 0.f}, c = {0.f, 0.f, 0.f, 0.f};
        if (ok) { a = *(const float4*)(rawp + gy * WIM + 4 * pg3[jj]);
                  c = *(const float4*)(clipp + gy * WIM + 4 * pg3[jj]); }
        vr[jj] = a; vc[jj] = c;
      }
#pragma unroll
      for (int jj = 0; jj < 2; jj++) {
        int gy = y0 - 2 + vrow[jj];
        float4 v = {0.f, 0.f, 0.f, 0.f};
        if (va[jj] && gy >= 0 && gy < HIM)
          v = *(const float4*)(objp + gy * WIM + 4 * vg[jj]);
        vo[jj] = v;
      }
#pragma unroll
      for (int jj = 0; jj < 2; jj++) {
        if (pra[jj]) {
          *(float4*)&s_raw[prow[jj] * LDW + 4 + 4 * pg3[jj]] = vr[jj];
          *(float4*)&s_clip[prow[jj] * LDW + 4 + 4 * pg3[jj]] = vc[jj];
        }
      }
#pragma unroll
      for (int jj = 0; jj < 2; jj++) {
        if (va[jj]) *(float4*)&s_po[vrow[jj] * LDW + 4 + 4 * vg[jj]] = vo[jj];
      }
    }
    __syncthreads();

    if (cact) {
      float a0 = 0.f, a1 = 0.f, a2 = 0.f, a3 = 0.f;
      int ub = rbase + 3 * part;
#pragma unroll
      for (int u = 0; u < 3; u++) {
        const float* rp = &s_raw[(ub + u) * LDW + x0];
        const float* cl = &s_clip[(ub + u) * LDW + x0];
        float rw[12], cc[12];
        *(float4*)&rw[0] = *(const float4*)rp;
        *(float4*)&rw[4] = *(const float4*)(rp + 4);
        *(float4*)&rw[8] = *(const float4*)(rp + 8);
        *(float4*)&cc[0] = *(const float4*)cl;
        *(float4*)&cc[4] = *(const float4*)(cl + 4);
        *(float4*)&cc[8] = *(const float4*)(cl + 8);
        const float* Cr = &s_C[(3 * part + u) * 9];
#pragma unroll
        for (int v = 0; v < 9; v++) {
          float wr = Cr[v], wc = Cr[81 + v];
          a0 += rw[v] * wr + cc[v] * wc;
          a1 += rw[v + 1] * wr + cc[v + 1] * wc;
          a2 += rw[v + 2] * wr + cc[v + 2] * wc;
          a3 += rw[v + 3] * wr + cc[v + 3] * wc;
        }
      }
      int ndd = (part == 2) ? 1 : 2;
      int dd0 = 2 * part;
      for (int dd = 0; dd < ndd; dd++) {
        int dr = dd0 + dd;
        const float* pp = &s_po[(rbase + dr) * LDW + x0];
        float po[12];
        *(float4*)&po[0] = *(const float4*)pp;
        *(float4*)&po[4] = *(const float4*)(pp + 4);
        *(float4*)&po[8] = *(const float4*)(pp + 8);
        const float* Cp = &s_C[162 + dr * 5];
#pragma unroll
        for (int d = 0; d < 5; d++) {
          float w = Cp[d];
          a0 += po[d + 2] * w;
          a1 += po[d + 3] * w;
          a2 += po[d + 4] * w;
          a3 += po[d + 5] * w;
        }
      }
      float4 p4 = {a0, a1, a2, a3};
      *(float4*)&s_part[t * 4] = p4;
    }
    __syncthreads();

    if (t < 160) {
      float4 p0 = *(const float4*)&s_part[(0 * 160 + t) * 4];
      float4 p1 = *(const float4*)&s_part[(1 * 160 + t) * 4];
      float4 p2 = *(const float4*)&s_part[(2 * 160 + t) * 4];
      float c187 = s_C[187];
      float a0 = p0.x + p1.x + p2.x + c187;
      float a1 = p0.y + p1.y + p2.y + c187;
      float a2 = p0.z + p1.z + p2.z + c187;
      float a3 = p0.w + p1.w + p2.w + c187;
      int y = y0 + 5 * rrow4;
      if (y != 0) {
        float* op = cpb + (size_t)(12 * half + 4 * tt + rrow4) * 1920 + 4 * rg;
        if (rg == 0) { op[2] = a2; op[3] = a3; }
        else if (rg == 39) { op[0] = a0; op[1] = a1; }
        else { float4 o4 = {a0, a1, a2, a3}; *(float4*)op = o4; }
      }
    }
  }
}

// ============ kernel 3: boundary fixup — strip-staged, balanced (R11-proven) ============
__global__ __launch_bounds__(256) void k_fix(
    const float* __restrict__ draw, const float* __restrict__ dclip,
    const float* __restrict__ obj,
    const float* __restrict__ c1w, const float* __restrict__ c1b,
    const float* __restrict__ attn, const float* __restrict__ wsC,
    float* __restrict__ cpano) {
  __shared__ float s_top[2][5][168];
  __shared__ float s_L[2][120][13];
  __shared__ float s_R[2][120][13];
  __shared__ float s_pdt[3][168];
  __shared__ float s_pdL[4][120];
  __shared__ float s_pdR[4][120];
  __shared__ float s_w1[50], s_kd[50];

  int bi = blockIdx.x;
  int b = bi / NAV, i = bi - b * NAV;
  int t = threadIdx.x;
  const size_t plane = (size_t)bi * HIM * WIM;
  const float* rawp = draw + plane;
  const float* clipp = dclip + plane;
  const float* objp = obj + plane;
  float attn_bi = attn[bi];
  float bias = c1b[i];

  if (t < 50) { s_w1[t] = c1w[i * 50 + t]; s_kd[t] = wsC[(size_t)bi * 240 + 188 + t]; }
  if (t < 80) { int a = t / 40, rem = t - 40 * a; int r = rem / 8, hc = rem & 7;
    s_top[a][r][hc < 4 ? hc : 160 + hc] = 0.f; }
  else if (t < 104) { int rem = t - 80; int r = rem / 8, hc = rem & 7;
    s_pdt[r][hc < 4 ? hc : 160 + hc] = 0.f; }
  for (int it = t; it < 2 * 2 * 120 * 7; it += 256) {
    int side = it / 1680, rem = it - 1680 * side;
    int a = rem / 840; rem -= 840 * a;
    int row = rem / 7, jj = rem - 7 * row;
    if (side == 0) s_L[a][row][jj < 2 ? jj : 6 + jj] = 0.f;
    else           s_R[a][row][6 + jj] = 0.f;
  }
  for (int it = t; it < 400; it += 256) {
    int a = it / 200, rem = it - 200 * a;
    int r = rem / 40, g = rem - 40 * r;
    const float* src = a ? clipp : rawp;
    *(float4*)&s_top[a][r][4 + 4 * g] = *(const float4*)(src + r * WIM + 4 * g);
  }
  for (int it = t; it < 2 * 2 * 120 * 6; it += 256) {
    int side = it / 1440, rem = it - 1440 * side;
    int a = rem / 720; rem -= 720 * a;
    int row = rem / 6, c = rem - 6 * row;
    const float* src = a ? clipp : rawp;
    if (side == 0) s_L[a][row][2 + c] = src[row * WIM + c];
    else           s_R[a][row][c] = src[row * WIM + 154 + c];
  }
  __syncthreads();

  for (int it = t; it < 480; it += 256) {
    int r = it / 160, x = it - 160 * r;
    float v = 0.f;
#pragma unroll
    for (int c = 0; c < 5; c++) {
      int rr = r - 2 + c;
      if (rr >= 0) {
#pragma unroll
        for (int d = 0; d < 5; d++) {
          int j = 2 + x + d;
          v += s_w1[c * 5 + d] * s_top[0][rr][j] + s_w1[25 + c * 5 + d] * s_top[1][rr][j];
        }
      }
    }
    s_pdt[r][4 + x] = bias + v;
  }
  for (int it = t; it < 460; it += 256) {
    int c = it / 115, y = 3 + (it - 115 * c);
    float v = 0.f;
#pragma unroll
    for (int cp = 0; cp < 5; cp++) {
      int rr = y - 2 + cp;
#pragma unroll
      for (int d = 0; d < 5; d++)
        v += s_w1[cp * 5 + d] * s_L[0][rr][c + d] + s_w1[25 + cp * 5 + d] * s_L[1][rr][c + d];
    }
    s_pdL[c][y] = bias + v;
  }
  for (int it = t; it < 460; it += 256) {
    int c = it / 115, y = 3 + (it - 115 * c);
    float v = 0.f;
#pragma unroll
    for (int cp = 0; cp < 5; cp++) {
      int rr = y - 2 + cp;
#pragma unroll
      for (int d = 0; d < 5; d++)
        v += s_w1[cp * 5 + d] * s_R[0][rr][c + d] + s_w1[25 + cp * 5 + d] * s_R[1][rr][c + d];
    }
    s_pdR[c][y] = bias + v;
  }
  __syncthreads();

  if (t < 252) {
    int y, x;
    if (t < 160) { y = 0; x = t; }
    else {
      int k = t - 160;
      int ri = k >> 2, xi = k & 3;
      y = 5 * (ri + 1);
      x = xi < 2 ? xi : 156 + xi;
    }
    float acc = 0.f;
    if (y == 0) {
#pragma unroll
      for (int a = 2; a < 5; a++)
#pragma unroll
        for (int bb2 = 0; bb2 < 5; bb2++)
          acc += s_kd[a * 5 + bb2] * s_pdt[a - 2][2 + x + bb2];
    } else {
#pragma unroll
      for (int a = 0; a < 5; a++) {
        int ry = y + a - 2;
#pragma unroll
        for (int bb2 = 0; bb2 < 5; bb2++) {
          int q = x + bb2 - 2;
          if (q < 0 || q >= 160) continue;
          float pdv = (q < 4) ? s_pdL[q][ry] : s_pdR[q - 156][ry];
          acc += s_kd[a * 5 + bb2] * pdv;
        }
      }
    }
#pragma unroll
    for (int dd = 0; dd < 5; dd++) {
      int ry = y + dd - 2;
      if (ry < 0 || ry >= HIM) continue;
#pragma unroll
      for (int d = 0; d < 5; d++) {
        int rx = x + d - 2;
        if (rx < 0 || rx >= WIM) continue;
        acc += s_kd[25 + dd * 5 + d] * objp[ry * WIM + rx];
      }
    }
    acc *= attn_bi;
    int q2 = i / 12, cw = i - 12 * q2;
    cpano[((size_t)b * 72 + (2 - q2) * 24 + y / 5) * 1920 + cw * WIM + x] = acc;
  }
}

// ============ kernel 4: conv2_1 on compact pano, both roll paths (512 th) ============
__global__ __launch_bounds__(512) void k_c21(
    const float* __restrict__ cpano, const float* __restrict__ w21,
    const float* __restrict__ b21, float* __restrict__ y1) {
  __shared__ float s_rows[5][1920];
  int t = threadIdx.x;
  int b = blockIdx.x, oy = blockIdx.y;
  const float* pp = cpano + (size_t)b * 72 * 1920;
  for (int tt = t; tt < 2400; tt += 512) {
    int ky = tt / 480, g = tt - 480 * ky;
    *(float4*)&s_rows[ky][4 * g] = *(const float4*)&pp[(size_t)(oy + 2 * ky) * 1920 + 4 * g];
  }
  float w[25];
#pragma unroll
  for (int k = 0; k < 25; k++) w[k] = w21[k];
  float bb = b21[0];
  __syncthreads();
  for (int tt = t; tt < 538; tt += 512) {
    int p = tt / 269, ox = tt - 269 * p;
    int shift = p ? 1760 : 0;
    float acc = bb;
#pragma unroll
    for (int ky = 0; ky < 5; ky++)
#pragma unroll
      for (int kx = 0; kx < 5; kx++) {
        int X = 7 * ox + 10 * kx + shift;
        if (X >= 1920) X -= 1920;
        acc += w[ky * 5 + kx] * s_rows[ky][X];
      }
    y1[((size_t)(p * B + b) * 64 + oy) * 269 + ox] = acc;
  }
}

// ============ kernel 5: fused pools+conv2_2 (both paths) + vf softmax ============
__global__ __launch_bounds__(512) void k_tailvf(
    const float* __restrict__ y1, const float* __restrict__ w22,
    const float* __restrict__ b22, const int* __restrict__ nav_idx,
    float* __restrict__ out_vf, float* __restrict__ out_mask) {
  __shared__ float s_y2[2][21][90];
  __shared__ float s_y3[2][10][44];
  __shared__ float s_vf2[2][36];
  __shared__ float s_v[36];
  __shared__ float s_inv;
  int t = threadIdx.x;
  int b = blockIdx.x;
  int p = t >> 8, tp = t & 255;
  const float* yp = y1 + (size_t)(p * B + b) * 64 * 269;
  for (int idx = tp; idx < 21 * 89; idx += 256) {
    int py = idx / 89, px = idx - 89 * py;
    float s = 0.f;
    for (int dy = 0; dy < 3; dy++)
      for (int dx = 0; dx < 3; dx++)
        s += yp[(3 * py + dy) * 269 + 3 * px + dx];
    s_y2[p][py][px] = s * (1.0f / 9.0f);
  }
  __syncthreads();
  for (int idx = tp; idx < 10 * 43; idx += 256) {
    int qy = idx / 43, qx = idx - 43 * qy;
    float a = b22[0];
#pragma unroll
    for (int ky = 0; ky < 3; ky++)
#pragma unroll
      for (int kx = 0; kx < 3; kx++)
        a += w22[ky * 3 + kx] * s_y2[p][2 * qy + ky][2 * qx + 2 * kx];
    s_y3[p][qy][qx] = a;
  }
  __syncthreads();
  if (tp < 36) {
    int uy = tp / 12, ux = tp - 12 * uy;
    float s = 0.f;
    for (int dy = 0; dy < 3; dy++)
      for (int dx = 0; dx < 9; dx++)
        s += s_y3[p][3 * uy + dy][3 * ux + dx];
    s_vf2[p][tp] = s * (1.0f / 27.0f);
  }
  __syncthreads();
  if (t < 36) {
    int u = t / 12, x = t - 12 * u;
    float v1 = s_vf2[0][(2 - u) * 12 + x];
    float v2 = s_vf2[1][(2 - u) * 12 + (x + 1) % 12];
    s_v[t] = 0.5f * (v1 + v2) * 0.1f;
  }
  __syncthreads();
  if (t == 0) {
    float m = -1e30f;
    for (int i = 0; i < 36; i++) m = fmaxf(m, s_v[i]);
    float s = 0.f;
    for (int i = 0; i < 36; i++) { s_v[i] = expf(s_v[i] - m); s += s_v[i]; }
    s_inv = 1.0f / s;
  }
  __syncthreads();
  if (t < 36) {
    out_vf[b * 36 + t] = s_v[t] * s_inv;
    float m = 0.f;
    for (int e = 0; e < 8; e++)
      if (nav_idx[b * 8 + e] == t) m = 1.0f;
    out_mask[b * 36 + t] = m;
  }
}

// ============ kernel 6: LSTM, 512 blocks (1 unit each), f4 weight loads ============
__global__ __launch_bounds__(256) void k_lstm(
    const float* __restrict__ ctx, const float* __restrict__ vf,
    const float* __restrict__ dfa, const float* __restrict__ pre,
    const float* __restrict__ h0, const float* __restrict__ c0,
    const float* __restrict__ wih, const float* __restrict__ whh,
    const float* __restrict__ bih, const float* __restrict__ bhh,
    float* __restrict__ h1, float* __restrict__ c1) {
  __shared__ float s_cat[B][1104];   // [0,589) cat, [592,1104) h0
  __shared__ float s_g[4][16];
  int t = threadIdx.x;
  int u = blockIdx.x;
  int g = t >> 6, l = t & 63;
  for (int idx = t; idx < B * 589; idx += 256) {
    int b = idx / 589, k = idx - 589 * b;
    float v;
    if (k < 512) v = ctx[b * 512 + k];
    else if (k < 548) v = vf[b * 36 + (k - 512)];
    else if (k < 552) v = dfa[b * 4 + (k - 548)];
    else v = pre[b * 37 + (k - 552)];
    s_cat[b][k] = v;
  }
  for (int idx = t; idx < B * 512; idx += 256) {
    int b = idx >> 9, k = idx & 511;
    s_cat[b][592 + k] = h0[b * 512 + k];
  }
  __syncthreads();
  int j = (g << 9) + u;
  float acc[B];
#pragma unroll
  for (int b = 0; b < B; b++) acc[b] = 0.f;
  const float* wi = wih + (size_t)j * 589;
#pragma unroll
  for (int it = 0; it < 3; it++) {
    int c = l + 64 * it;
    if (c < 147) {
      int k = 4 * c;
      float w0 = wi[k], w1 = wi[k + 1], w2 = wi[k + 2], w3 = wi[k + 3];
#pragma unroll
      for (int b = 0; b < B; b++) {
        float4 cc = *(const float4*)&s_cat[b][k];
        acc[b] += cc.x * w0 + cc.y * w1 + cc.z * w2 + cc.w * w3;
      }
    }
  }
  if (l == 0) {
    float w = wi[588];
#pragma unroll
    for (int b = 0; b < B; b++) acc[b] += w * s_cat[b][588];
  }
  const float* wh = whh + (size_t)j * 512;
#pragma unroll
  for (int it = 0; it < 2; it++) {
    int k = 4 * (l + 64 * it);
    float4 w4 = *(const float4*)&wh[k];
#pragma unroll
    for (int b = 0; b < B; b++) {
      float4 cc = *(const float4*)&s_cat[b][592 + k];
      acc[b] += cc.x * w4.x + cc.y * w4.y + cc.z * w4.z + cc.w * w4.w;
    }
  }
#pragma unroll
  for (int off = 1; off < 64; off <<= 1)
#pragma unroll
    for (int b = 0; b < B; b++) acc[b] += __shfl_xor(acc[b], off);
  if (l == 0) {
    float bb = bih[j] + bhh[j];
#pragma unroll
    for (int b = 0; b < B; b++) s_g[g][b] = acc[b] + bb;
  }
  __syncthreads();
  if (t < 16) {
    float gi = s_g[0][t], gf = s_g[1][t], gg = s_g[2][t], go = s_g[3][t];
    float c_old = c0[t * 512 + u];
    float si = 1.0f / (1.0f + expf(-gi));
    float sf = 1.0f / (1.0f + expf(-gf));
    float so = 1.0f / (1.0f + expf(-go));
    float cn = sf * c_old + si * tanhf(gg);
    h1[t * 512 + u] = so * tanhf(cn);
    c1[t * 512 + u] = cn;
  }
}

extern "C" void kernel_launch(void* const* d_in, const int* in_sizes, int n_in,
                              void* d_out, int out_size, void* d_ws, size_t ws_size,
                              hipStream_t stream) {
  const float* depth_raw  = (const float*)d_in[0];
  const float* depth_clip = (const float*)d_in[1];
  const float* obj_feat   = (const float*)d_in[2];
  const float* nnf        = (const float*)d_in[3];
  const float* pre        = (const float*)d_in[4];
  const float* h0         = (const float*)d_in[5];
  const float* c0         = (const float*)d_in[6];
  const float* ctx        = (const float*)d_in[7];
  const int*   nav_idx    = (const int*)d_in[8];
  const float* c1w        = (const float*)d_in[9];
  const float* c1b        = (const float*)d_in[10];
  const float* fc1w       = (const float*)d_in[11];
  const float* fc1b       = (const float*)d_in[12];
  const float* fc2w       = (const float*)d_in[13];
  const float* fc2b       = (const float*)d_in[14];
  const float* dynf       = (const float*)d_in[15];
  const float* w21        = (const float*)d_in[16];
  const float* b21        = (const float*)d_in[17];
  const float* w22        = (const float*)d_in[18];
  const float* b22        = (const float*)d_in[19];
  const float* wih        = (const float*)d_in[20];
  const float* whh        = (const float*)d_in[21];
  const float* bih        = (const float*)d_in[22];
  const float* bhh        = (const float*)d_in[23];

  float* ws = (float*)d_ws;
  float* attn   = ws;
  float* dfa    = ws + 576;
  float* y1     = ws + 1792;
  float* cpano  = ws + 552704;
  float* wsC    = ws + 2764544;

  float* out = (float*)d_out;
  float* out_h1   = out;
  float* out_c1   = out + 8192;
  float* out_vf   = out + 16384;
  float* out_mask = out + 16960;

  k_comp<<<B * NAV, 192, 0, stream>>>(nnf, ctx, fc1w, fc1b, fc2w, fc2b,
                                      c1w, c1b, dynf, attn, dfa, wsC);
  k_conv<<<B * NAV * 2, 512, 0, stream>>>(depth_raw, depth_clip, obj_feat, wsC, cpano);
  k_fix<<<B * NAV, 256, 0, stream>>>(depth_raw, depth_clip, obj_feat,
                                     c1w, c1b, attn, wsC, cpano);
  k_c21<<<dim3(B, 64), 512, 0, stream>>>(cpano, w21, b21, y1);
  k_tailvf<<<B, 512, 0, stream>>>(y1, w22, b22, nav_idx, out_vf, out_mask);
  k_lstm<<<RH, 256, 0, stream>>>(ctx, out_vf, dfa, pre, h0, c0,
                                 wih, whh, bih, bhh, out_h1, out_c1);
}

// Round 20
// 126.640 us; speedup vs baseline: 1.0494x; 1.0494x over previous
//
#include <hip/hip_runtime.h>
#include <math.h>

#define B 16
#define NAV 36
#define HIM 120
#define WIM 160
#define RH 512
#define NF 4
#define AE 37

// ---------------- workspace layout (floats) ----------------
// attn   : [B*NAV]            @ 0        (576)
// dfa    : [B*NF]             @ 576      (64)
// y1     : [2][B][64][269]    @ 1792     (550912)
// cpano  : [B][72][1920]      @ 552704   (2211840)
// wsC    : [576][240]         @ 2764544  (138240)

// ============ kernel 1: attn softmax + dynamic-filter MLP ============
__global__ __launch_bounds__(128) void k_head(
    const float* __restrict__ nnf, const float* __restrict__ ctx,
    const float* __restrict__ fc1w, const float* __restrict__ fc1b,
    const float* __restrict__ fc2w, const float* __restrict__ fc2b,
    float* __restrict__ attn, float* __restrict__ dfa) {
  int b = blockIdx.x;
  int t = threadIdx.x;  // 128 threads
  __shared__ float s_ctx[RH];
  __shared__ float s_v[NAV];
  __shared__ float s_hid[128];
  __shared__ float s_l[NF];
  __shared__ float s_inv[2];

  if (t < NAV) s_v[t] = nnf[b * NAV + t];
  for (int k = t; k < RH; k += 128) s_ctx[k] = ctx[b * RH + k];
  __syncthreads();

  if (t == 0) {
    float m = -1e30f;
    for (int i = 0; i < NAV; i++) m = fmaxf(m, s_v[i]);
    float s = 0.f;
    for (int i = 0; i < NAV; i++) { s_v[i] = expf(s_v[i] - m); s += s_v[i]; }
    s_inv[0] = 1.0f / s;
  }
  float acc = fc1b[t];
  const float* wr = fc1w + t * RH;
  for (int k = 0; k < RH; k++) acc += s_ctx[k] * wr[k];
  s_hid[t] = fmaxf(acc, 0.0f);
  __syncthreads();

  if (t < NAV) attn[b * NAV + t] = s_v[t] * s_inv[0];
  if (t < NF) {
    float a = fc2b[t];
    const float* w2 = fc2w + t * 128;
    for (int k = 0; k < 128; k++) a += s_hid[k] * w2[k];
    s_l[t] = a;
  }
  __syncthreads();
  if (t == 0) {
    float m = fmaxf(fmaxf(s_l[0], s_l[1]), fmaxf(s_l[2], s_l[3]));
    float s = 0.f;
    for (int f = 0; f < NF; f++) { s_l[f] = expf(s_l[f] - m); s += s_l[f]; }
    s_inv[1] = 1.0f / s;
  }
  __syncthreads();
  if (t < NF) dfa[b * NF + t] = s_l[t] * s_inv[1];
}

// ============ kernel 2: compose weights: C9 = kd_pd (*) W1, per (b,i) ============
__global__ __launch_bounds__(192) void k_comp(
    const float* __restrict__ c1w, const float* __restrict__ c1b,
    const float* __restrict__ dynf,
    const float* __restrict__ attn, const float* __restrict__ dfa,
    float* __restrict__ wsC) {
  int bi = blockIdx.x;
  int b = bi / NAV, i = bi - b * NAV;
  int t = threadIdx.x;
  __shared__ float s_kd[50];
  __shared__ float s_w1[50];
  if (t < 50) {
    float a = 0.f;
    for (int f = 0; f < NF; f++) a += dfa[b * NF + f] * dynf[(f * NAV + i) * 50 + t];
    s_kd[t] = a;
    s_w1[t] = c1w[i * 50 + t];
  }
  __syncthreads();
  float attn_bi = attn[bi];
  float* o = wsC + (size_t)bi * 240;
  if (t < 162) {
    int ch = t < 81 ? 0 : 1;
    int uv = t - 81 * ch;
    int u = uv / 9, v = uv - 9 * u;
    float c = 0.f;
    for (int a = 0; a < 5; a++) {
      int cc = u - a; if (cc < 0 || cc > 4) continue;
      for (int bb = 0; bb < 5; bb++) {
        int d = v - bb; if (d < 0 || d > 4) continue;
        c += s_kd[a * 5 + bb] * s_w1[ch * 25 + cc * 5 + d];
      }
    }
    o[ch * 81 + uv] = c * attn_bi;
  } else if (t < 187) {
    o[t] = s_kd[25 + (t - 162)] * attn_bi;   // attn*kd_po
  } else if (t == 187) {
    float s2 = 0.f;
    for (int j = 0; j < 25; j++) s2 += s_kd[j];
    o[187] = attn_bi * c1b[i] * s2;
  }
  if (t < 50) o[188 + t] = s_kd[t];
}

// ============ kernel 3: composed 9x9 conv -> compact pano (R12 + LDW=168) ============
// 1152 blocks = (b,i,half), 512 threads, 3 tiles of advance-20, direct
// global->LDS staging, balanced 3-part partials, 2 barriers/tile.
// LDW=168: LDS 54.3KB -> ~3 blocks/CU. 168%4==0 keeps f4 alignment;
// 168==8 mod 32 keeps distinct row bank phase.
#define LDW 168
__global__ __launch_bounds__(512) void k_conv(
    const float* __restrict__ draw, const float* __restrict__ dclip,
    const float* __restrict__ obj,
    const float* __restrict__ wsC,
    float* __restrict__ cpano) {
  __shared__ __align__(16) float s_raw[24 * LDW];
  __shared__ __align__(16) float s_clip[24 * LDW];
  __shared__ __align__(16) float s_po[20 * LDW];
  __shared__ __align__(16) float s_part[1920];   // [part][160] float4
  __shared__ float s_C[188];

  int t = threadIdx.x;
  int bz = blockIdx.x;
  int half = bz & 1;
  int pi = bz >> 1;
  int b = pi / NAV, i = pi - b * NAV;
  int ybase = 60 * half;

  const size_t plane = (size_t)pi * HIM * WIM;
  const float* rawp = draw + plane;
  const float* clipp = dclip + plane;
  const float* objp = obj + plane;
  int q = i / 12, cw = i - 12 * q;
  float* cpb = cpano + ((size_t)b * 72 + (2 - q) * 24) * 1920 + cw * WIM;

  // prologue: composed weights + halo-col zeros (preserved across tiles)
  const float* cp = wsC + (size_t)pi * 240;
  if (t < 188) s_C[t] = cp[t];
  if (t < 384) {  // raw/clip: 2 arrays x 24 rows x 8 cols
    int ha = t < 192 ? 0 : 1, rem = t - 192 * ha;
    int r = rem >> 3, hc = rem & 7;
    int col = hc < 4 ? hc : 160 + hc;
    (ha ? s_clip : s_raw)[r * LDW + col] = 0.f;
  }
  if (t < 160) {  // po: 20 rows x 8 cols
    int r = t >> 3, hc = t & 7;
    int col = hc < 4 ? hc : 160 + hc;
    s_po[r * LDW + col] = 0.f;
  }

  // per-thread constant maps
  int prow[2], pg3[2]; bool pra[2];   // raw/clip: 960 f4 items = 24 rows x 40
#pragma unroll
  for (int jj = 0; jj < 2; jj++) {
    int idx = t + 512 * jj;
    pra[jj] = idx < 960;
    prow[jj] = idx / 40;
    pg3[jj] = idx - 40 * prow[jj];
  }
  int vrow[2], vg[2]; bool va[2];     // obj: 800 f4 items = 20 rows x 40
#pragma unroll
  for (int jj = 0; jj < 2; jj++) {
    int idx = t + 512 * jj;
    va[jj] = idx < 800;
    vrow[jj] = idx / 40;
    vg[jj] = idx - 40 * vrow[jj];
  }
  // compute map: part = t/160, pgc = t-160*part; row4 = pgc/40, gc = pgc%40
  int part = t / 160;                  // 0..2 active (t<480)
  int pgc = t - 160 * part;
  int row4 = pgc / 40;
  int gc = pgc - 40 * row4;
  int x0 = 4 * gc;
  int rbase = 5 * row4;
  bool cact = (t < 480);
  // reduce map (t<160)
  int rrow4 = t / 40;
  int rg = t - 40 * rrow4;

  for (int tt = 0; tt < 3; tt++) {
    int y0 = ybase + 20 * tt;
    // A: stage raw/clip/obj direct global->LDS (f4, 16B lane-stride)
    {
      float4 vr[2], vc[2], vo[2];
#pragma unroll
      for (int jj = 0; jj < 2; jj++) {
        int gy = y0 - 4 + prow[jj];
        bool ok = pra[jj] && gy >= 0 && gy < HIM;
        float4 a = {0.f, 0.f, 0.f, 0.f}, c = {0.f, 0.f, 0.f, 0.f};
        if (ok) { a = *(const float4*)(rawp + gy * WIM + 4 * pg3[jj]);
                  c = *(const float4*)(clipp + gy * WIM + 4 * pg3[jj]); }
        vr[jj] = a; vc[jj] = c;
      }
#pragma unroll
      for (int jj = 0; jj < 2; jj++) {
        int gy = y0 - 2 + vrow[jj];
        float4 v = {0.f, 0.f, 0.f, 0.f};
        if (va[jj] && gy >= 0 && gy < HIM)
          v = *(const float4*)(objp + gy * WIM + 4 * vg[jj]);
        vo[jj] = v;
      }
#pragma unroll
      for (int jj = 0; jj < 2; jj++) {
        if (pra[jj]) {
          *(float4*)&s_raw[prow[jj] * LDW + 4 + 4 * pg3[jj]] = vr[jj];
          *(float4*)&s_clip[prow[jj] * LDW + 4 + 4 * pg3[jj]] = vc[jj];
        }
      }
#pragma unroll
      for (int jj = 0; jj < 2; jj++) {
        if (va[jj]) *(float4*)&s_po[vrow[jj] * LDW + 4 + 4 * vg[jj]] = vo[jj];
      }
    }
    __syncthreads();

    // B: partial compute (480 threads): 3 u-rows + share of po rows
    if (cact) {
      float a0 = 0.f, a1 = 0.f, a2 = 0.f, a3 = 0.f;
      int ub = rbase + 3 * part;
#pragma unroll
      for (int u = 0; u < 3; u++) {
        const float* rp = &s_raw[(ub + u) * LDW + x0];
        const float* cl = &s_clip[(ub + u) * LDW + x0];
        float rw[12], cc[12];
        *(float4*)&rw[0] = *(const float4*)rp;
        *(float4*)&rw[4] = *(const float4*)(rp + 4);
        *(float4*)&rw[8] = *(const float4*)(rp + 8);
        *(float4*)&cc[0] = *(const float4*)cl;
        *(float4*)&cc[4] = *(const float4*)(cl + 4);
        *(float4*)&cc[8] = *(const float4*)(cl + 8);
        const float* Cr = &s_C[(3 * part + u) * 9];
#pragma unroll
        for (int v = 0; v < 9; v++) {
          float wr = Cr[v], wc = Cr[81 + v];
          a0 += rw[v] * wr + cc[v] * wc;
          a1 += rw[v + 1] * wr + cc[v + 1] * wc;
          a2 += rw[v + 2] * wr + cc[v + 2] * wc;
          a3 += rw[v + 3] * wr + cc[v + 3] * wc;
        }
      }
      int ndd = (part == 2) ? 1 : 2;
      int dd0 = 2 * part;
      for (int dd = 0; dd < ndd; dd++) {
        int dr = dd0 + dd;
        const float* pp = &s_po[(rbase + dr) * LDW + x0];
        float po[12];
        *(float4*)&po[0] = *(const float4*)pp;
        *(float4*)&po[4] = *(const float4*)(pp + 4);
        *(float4*)&po[8] = *(const float4*)(pp + 8);
        const float* Cp = &s_C[162 + dr * 5];
#pragma unroll
        for (int d = 0; d < 5; d++) {
          float w = Cp[d];
          a0 += po[d + 2] * w;
          a1 += po[d + 3] * w;
          a2 += po[d + 4] * w;
          a3 += po[d + 5] * w;
        }
      }
      float4 p4 = {a0, a1, a2, a3};
      *(float4*)&s_part[t * 4] = p4;
    }
    __syncthreads();

    // C: reduce partials + store (160 threads)
    if (t < 160) {
      float4 p0 = *(const float4*)&s_part[(0 * 160 + t) * 4];
      float4 p1 = *(const float4*)&s_part[(1 * 160 + t) * 4];
      float4 p2 = *(const float4*)&s_part[(2 * 160 + t) * 4];
      float c187 = s_C[187];
      float a0 = p0.x + p1.x + p2.x + c187;
      float a1 = p0.y + p1.y + p2.y + c187;
      float a2 = p0.z + p1.z + p2.z + c187;
      float a3 = p0.w + p1.w + p2.w + c187;
      int y = y0 + 5 * rrow4;
      if (y != 0) {
        float* op = cpb + (size_t)(12 * half + 4 * tt + rrow4) * 1920 + 4 * rg;
        if (rg == 0) { op[2] = a2; op[3] = a3; }
        else if (rg == 39) { op[0] = a0; op[1] = a1; }
        else { float4 o4 = {a0, a1, a2, a3}; *(float4*)op = o4; }
      }
    }
  }
}

// ============ kernel 4: boundary fixup — strip-staged, balanced (R11-proven) ============
__global__ __launch_bounds__(256) void k_fix(
    const float* __restrict__ draw, const float* __restrict__ dclip,
    const float* __restrict__ obj,
    const float* __restrict__ c1w, const float* __restrict__ c1b,
    const float* __restrict__ attn, const float* __restrict__ wsC,
    float* __restrict__ cpano) {
  __shared__ float s_top[2][5][168];
  __shared__ float s_L[2][120][13];
  __shared__ float s_R[2][120][13];
  __shared__ float s_pdt[3][168];
  __shared__ float s_pdL[4][120];
  __shared__ float s_pdR[4][120];
  __shared__ float s_w1[50], s_kd[50];

  int bi = blockIdx.x;
  int b = bi / NAV, i = bi - b * NAV;
  int t = threadIdx.x;
  const size_t plane = (size_t)bi * HIM * WIM;
  const float* rawp = draw + plane;
  const float* clipp = dclip + plane;
  const float* objp = obj + plane;
  float attn_bi = attn[bi];
  float bias = c1b[i];

  if (t < 50) { s_w1[t] = c1w[i * 50 + t]; s_kd[t] = wsC[(size_t)bi * 240 + 188 + t]; }
  if (t < 80) { int a = t / 40, rem = t - 40 * a; int r = rem / 8, hc = rem & 7;
    s_top[a][r][hc < 4 ? hc : 160 + hc] = 0.f; }
  else if (t < 104) { int rem = t - 80; int r = rem / 8, hc = rem & 7;
    s_pdt[r][hc < 4 ? hc : 160 + hc] = 0.f; }
  for (int it = t; it < 2 * 2 * 120 * 7; it += 256) {
    int side = it / 1680, rem = it - 1680 * side;
    int a = rem / 840; rem -= 840 * a;
    int row = rem / 7, jj = rem - 7 * row;
    if (side == 0) s_L[a][row][jj < 2 ? jj : 6 + jj] = 0.f;
    else           s_R[a][row][6 + jj] = 0.f;
  }
  for (int it = t; it < 400; it += 256) {
    int a = it / 200, rem = it - 200 * a;
    int r = rem / 40, g = rem - 40 * r;
    const float* src = a ? clipp : rawp;
    *(float4*)&s_top[a][r][4 + 4 * g] = *(const float4*)(src + r * WIM + 4 * g);
  }
  for (int it = t; it < 2 * 2 * 120 * 6; it += 256) {
    int side = it / 1440, rem = it - 1440 * side;
    int a = rem / 720; rem -= 720 * a;
    int row = rem / 6, c = rem - 6 * row;
    const float* src = a ? clipp : rawp;
    if (side == 0) s_L[a][row][2 + c] = src[row * WIM + c];
    else           s_R[a][row][c] = src[row * WIM + 154 + c];
  }
  __syncthreads();

  for (int it = t; it < 480; it += 256) {
    int r = it / 160, x = it - 160 * r;
    float v = 0.f;
#pragma unroll
    for (int c = 0; c < 5; c++) {
      int rr = r - 2 + c;
      if (rr >= 0) {
#pragma unroll
        for (int d = 0; d < 5; d++) {
          int j = 2 + x + d;
          v += s_w1[c * 5 + d] * s_top[0][rr][j] + s_w1[25 + c * 5 + d] * s_top[1][rr][j];
        }
      }
    }
    s_pdt[r][4 + x] = bias + v;
  }
  for (int it = t; it < 460; it += 256) {
    int c = it / 115, y = 3 + (it - 115 * c);
    float v = 0.f;
#pragma unroll
    for (int cp = 0; cp < 5; cp++) {
      int rr = y - 2 + cp;
#pragma unroll
      for (int d = 0; d < 5; d++)
        v += s_w1[cp * 5 + d] * s_L[0][rr][c + d] + s_w1[25 + cp * 5 + d] * s_L[1][rr][c + d];
    }
    s_pdL[c][y] = bias + v;
  }
  for (int it = t; it < 460; it += 256) {
    int c = it / 115, y = 3 + (it - 115 * c);
    float v = 0.f;
#pragma unroll
    for (int cp = 0; cp < 5; cp++) {
      int rr = y - 2 + cp;
#pragma unroll
      for (int d = 0; d < 5; d++)
        v += s_w1[cp * 5 + d] * s_R[0][rr][c + d] + s_w1[25 + cp * 5 + d] * s_R[1][rr][c + d];
    }
    s_pdR[c][y] = bias + v;
  }
  __syncthreads();

  if (t < 252) {
    int y, x;
    if (t < 160) { y = 0; x = t; }
    else {
      int k = t - 160;
      int ri = k >> 2, xi = k & 3;
      y = 5 * (ri + 1);
      x = xi < 2 ? xi : 156 + xi;
    }
    float acc = 0.f;
    if (y == 0) {
#pragma unroll
      for (int a = 2; a < 5; a++)
#pragma unroll
        for (int bb2 = 0; bb2 < 5; bb2++)
          acc += s_kd[a * 5 + bb2] * s_pdt[a - 2][2 + x + bb2];
    } else {
#pragma unroll
      for (int a = 0; a < 5; a++) {
        int ry = y + a - 2;
#pragma unroll
        for (int bb2 = 0; bb2 < 5; bb2++) {
          int q = x + bb2 - 2;
          if (q < 0 || q >= 160) continue;
          float pdv = (q < 4) ? s_pdL[q][ry] : s_pdR[q - 156][ry];
          acc += s_kd[a * 5 + bb2] * pdv;
        }
      }
    }
#pragma unroll
    for (int dd = 0; dd < 5; dd++) {
      int ry = y + dd - 2;
      if (ry < 0 || ry >= HIM) continue;
#pragma unroll
      for (int d = 0; d < 5; d++) {
        int rx = x + d - 2;
        if (rx < 0 || rx >= WIM) continue;
        acc += s_kd[25 + dd * 5 + d] * objp[ry * WIM + rx];
      }
    }
    acc *= attn_bi;
    int q2 = i / 12, cw = i - 12 * q2;
    cpano[((size_t)b * 72 + (2 - q2) * 24 + y / 5) * 1920 + cw * WIM + x] = acc;
  }
}

// ============ kernel 5: conv2_1 on compact pano, both roll paths ============
__global__ __launch_bounds__(256) void k_c21(
    const float* __restrict__ cpano, const float* __restrict__ w21,
    const float* __restrict__ b21, float* __restrict__ y1) {
  __shared__ float s_rows[5][1920];
  int t = threadIdx.x;
  int b = blockIdx.x, oy = blockIdx.y;
  const float* pp = cpano + (size_t)b * 72 * 1920;
  for (int tt = t; tt < 2400; tt += 256) {
    int ky = tt / 480, g = tt - 480 * ky;
    *(float4*)&s_rows[ky][4 * g] = *(const float4*)&pp[(size_t)(oy + 2 * ky) * 1920 + 4 * g];
  }
  float w[25];
#pragma unroll
  for (int k = 0; k < 25; k++) w[k] = w21[k];
  float bb = b21[0];
  __syncthreads();
  for (int tt = t; tt < 538; tt += 256) {
    int p = tt / 269, ox = tt - 269 * p;
    int shift = p ? 1760 : 0;
    float acc = bb;
#pragma unroll
    for (int ky = 0; ky < 5; ky++)
#pragma unroll
      for (int kx = 0; kx < 5; kx++) {
        int X = 7 * ox + 10 * kx + shift;
        if (X >= 1920) X -= 1920;
        acc += w[ky * 5 + kx] * s_rows[ky][X];
      }
    y1[((size_t)(p * B + b) * 64 + oy) * 269 + ox] = acc;
  }
}

// ============ kernel 6: fused pools+conv2_2 (both paths) + vf softmax ============
__global__ __launch_bounds__(512) void k_tailvf(
    const float* __restrict__ y1, const float* __restrict__ w22,
    const float* __restrict__ b22, const int* __restrict__ nav_idx,
    float* __restrict__ out_vf, float* __restrict__ out_mask) {
  __shared__ float s_y2[2][21][90];
  __shared__ float s_y3[2][10][44];
  __shared__ float s_vf2[2][36];
  __shared__ float s_v[36];
  __shared__ float s_inv;
  int t = threadIdx.x;
  int b = blockIdx.x;
  int p = t >> 8, tp = t & 255;
  const float* yp = y1 + (size_t)(p * B + b) * 64 * 269;
  for (int idx = tp; idx < 21 * 89; idx += 256) {
    int py = idx / 89, px = idx - 89 * py;
    float s = 0.f;
    for (int dy = 0; dy < 3; dy++)
      for (int dx = 0; dx < 3; dx++)
        s += yp[(3 * py + dy) * 269 + 3 * px + dx];
    s_y2[p][py][px] = s * (1.0f / 9.0f);
  }
  __syncthreads();
  for (int idx = tp; idx < 10 * 43; idx += 256) {
    int qy = idx / 43, qx = idx - 43 * qy;
    float a = b22[0];
#pragma unroll
    for (int ky = 0; ky < 3; ky++)
#pragma unroll
      for (int kx = 0; kx < 3; kx++)
        a += w22[ky * 3 + kx] * s_y2[p][2 * qy + ky][2 * qx + 2 * kx];
    s_y3[p][qy][qx] = a;
  }
  __syncthreads();
  if (tp < 36) {
    int uy = tp / 12, ux = tp - 12 * uy;
    float s = 0.f;
    for (int dy = 0; dy < 3; dy++)
      for (int dx = 0; dx < 9; dx++)
        s += s_y3[p][3 * uy + dy][3 * ux + dx];
    s_vf2[p][tp] = s * (1.0f / 27.0f);
  }
  __syncthreads();
  if (t < 36) {
    int u = t / 12, x = t - 12 * u;
    float v1 = s_vf2[0][(2 - u) * 12 + x];
    float v2 = s_vf2[1][(2 - u) * 12 + (x + 1) % 12];
    s_v[t] = 0.5f * (v1 + v2) * 0.1f;
  }
  __syncthreads();
  if (t == 0) {
    float m = -1e30f;
    for (int i = 0; i < 36; i++) m = fmaxf(m, s_v[i]);
    float s = 0.f;
    for (int i = 0; i < 36; i++) { s_v[i] = expf(s_v[i] - m); s += s_v[i]; }
    s_inv = 1.0f / s;
  }
  __syncthreads();
  if (t < 36) {
    out_vf[b * 36 + t] = s_v[t] * s_inv;
    float m = 0.f;
    for (int e = 0; e < 8; e++)
      if (nav_idx[b * 8 + e] == t) m = 1.0f;
    out_mask[b * 36 + t] = m;
  }
}

// ============ kernel 7: LSTM, 512 blocks (1 unit each), f4 weight loads ============
__global__ __launch_bounds__(256) void k_lstm(
    const float* __restrict__ ctx, const float* __restrict__ vf,
    const float* __restrict__ dfa, const float* __restrict__ pre,
    const float* __restrict__ h0, const float* __restrict__ c0,
    const float* __restrict__ wih, const float* __restrict__ whh,
    const float* __restrict__ bih, const float* __restrict__ bhh,
    float* __restrict__ h1, float* __restrict__ c1) {
  __shared__ float s_cat[B][1104];   // [0,589) cat, [592,1104) h0
  __shared__ float s_g[4][16];
  int t = threadIdx.x;
  int u = blockIdx.x;
  int g = t >> 6, l = t & 63;
  for (int idx = t; idx < B * 589; idx += 256) {
    int b = idx / 589, k = idx - 589 * b;
    float v;
    if (k < 512) v = ctx[b * 512 + k];
    else if (k < 548) v = vf[b * 36 + (k - 512)];
    else if (k < 552) v = dfa[b * 4 + (k - 548)];
    else v = pre[b * 37 + (k - 552)];
    s_cat[b][k] = v;
  }
  for (int idx = t; idx < B * 512; idx += 256) {
    int b = idx >> 9, k = idx & 511;
    s_cat[b][592 + k] = h0[b * 512 + k];
  }
  __syncthreads();
  int j = (g << 9) + u;
  float acc[B];
#pragma unroll
  for (int b = 0; b < B; b++) acc[b] = 0.f;
  const float* wi = wih + (size_t)j * 589;
#pragma unroll
  for (int it = 0; it < 3; it++) {
    int c = l + 64 * it;
    if (c < 147) {
      int k = 4 * c;
      float w0 = wi[k], w1 = wi[k + 1], w2 = wi[k + 2], w3 = wi[k + 3];
#pragma unroll
      for (int b = 0; b < B; b++) {
        float4 cc = *(const float4*)&s_cat[b][k];
        acc[b] += cc.x * w0 + cc.y * w1 + cc.z * w2 + cc.w * w3;
      }
    }
  }
  if (l == 0) {
    float w = wi[588];
#pragma unroll
    for (int b = 0; b < B; b++) acc[b] += w * s_cat[b][588];
  }
  const float* wh = whh + (size_t)j * 512;
#pragma unroll
  for (int it = 0; it < 2; it++) {
    int k = 4 * (l + 64 * it);
    float4 w4 = *(const float4*)&wh[k];
#pragma unroll
    for (int b = 0; b < B; b++) {
      float4 cc = *(const float4*)&s_cat[b][592 + k];
      acc[b] += cc.x * w4.x + cc.y * w4.y + cc.z * w4.z + cc.w * w4.w;
    }
  }
#pragma unroll
  for (int off = 1; off < 64; off <<= 1)
#pragma unroll
    for (int b = 0; b < B; b++) acc[b] += __shfl_xor(acc[b], off);
  if (l == 0) {
    float bb = bih[j] + bhh[j];
#pragma unroll
    for (int b = 0; b < B; b++) s_g[g][b] = acc[b] + bb;
  }
  __syncthreads();
  if (t < 16) {
    float gi = s_g[0][t], gf = s_g[1][t], gg = s_g[2][t], go = s_g[3][t];
    float c_old = c0[t * 512 + u];
    float si = 1.0f / (1.0f + expf(-gi));
    float sf = 1.0f / (1.0f + expf(-gf));
    float so = 1.0f / (1.0f + expf(-go));
    float cn = sf * c_old + si * tanhf(gg);
    h1[t * 512 + u] = so * tanhf(cn);
    c1[t * 512 + u] = cn;
  }
}

extern "C" void kernel_launch(void* const* d_in, const int* in_sizes, int n_in,
                              void* d_out, int out_size, void* d_ws, size_t ws_size,
                              hipStream_t stream) {
  const float* depth_raw  = (const float*)d_in[0];
  const float* depth_clip = (const float*)d_in[1];
  const float* obj_feat   = (const float*)d_in[2];
  const float* nnf        = (const float*)d_in[3];
  const float* pre        = (const float*)d_in[4];
  const float* h0         = (const float*)d_in[5];
  const float* c0         = (const float*)d_in[6];
  const float* ctx        = (const float*)d_in[7];
  const int*   nav_idx    = (const int*)d_in[8];
  const float* c1w        = (const float*)d_in[9];
  const float* c1b        = (const float*)d_in[10];
  const float* fc1w       = (const float*)d_in[11];
  const float* fc1b       = (const float*)d_in[12];
  const float* fc2w       = (const float*)d_in[13];
  const float* fc2b       = (const float*)d_in[14];
  const float* dynf       = (const float*)d_in[15];
  const float* w21        = (const float*)d_in[16];
  const float* b21        = (const float*)d_in[17];
  const float* w22        = (const float*)d_in[18];
  const float* b22        = (const float*)d_in[19];
  const float* wih        = (const float*)d_in[20];
  const float* whh        = (const float*)d_in[21];
  const float* bih        = (const float*)d_in[22];
  const float* bhh        = (const float*)d_in[23];

  float* ws = (float*)d_ws;
  float* attn   = ws;
  float* dfa    = ws + 576;
  float* y1     = ws + 1792;
  float* cpano  = ws + 552704;
  float* wsC    = ws + 2764544;

  float* out = (float*)d_out;
  float* out_h1   = out;
  float* out_c1   = out + 8192;
  float* out_vf   = out + 16384;
  float* out_mask = out + 16960;

  k_head<<<B, 128, 0, stream>>>(nnf, ctx, fc1w, fc1b, fc2w, fc2b, attn, dfa);
  k_comp<<<B * NAV, 192, 0, stream>>>(c1w, c1b, dynf, attn, dfa, wsC);
  k_conv<<<B * NAV * 2, 512, 0, stream>>>(depth_raw, depth_clip, obj_feat, wsC, cpano);
  k_fix<<<B * NAV, 256, 0, stream>>>(depth_raw, depth_clip, obj_feat,
                                     c1w, c1b, attn, wsC, cpano);
  k_c21<<<dim3(B, 64), 256, 0, stream>>>(cpano, w21, b21, y1);
  k_tailvf<<<B, 512, 0, stream>>>(y1, w22, b22, nav_idx, out_vf, out_mask);
  k_lstm<<<RH, 256, 0, stream>>>(ctx, out_vf, dfa, pre, h0, c0,
                                 wih, whh, bih, bhh, out_h1, out_c1);
}

// Round 21
// 118.141 us; speedup vs baseline: 1.1249x; 1.0719x over previous
//
#include <hip/hip_runtime.h>
#include <math.h>

#define B 16
#define NAV 36
#define HIM 120
#define WIM 160
#define RH 512
#define NF 4
#define AE 37

// ---------------- workspace layout (floats) ----------------
// attn   : [B*NAV]            @ 0        (576)
// dfa    : [B*NF]             @ 576      (64)
// y1     : [2][B][64][269]    @ 1792     (550912)
// cpano  : [B][72][1920]      @ 552704   (2211840)
// wsC    : [576][240]         @ 2764544  (138240)

// ============ kernel 1: attn softmax + dynamic-filter MLP ============
__global__ __launch_bounds__(128) void k_head(
    const float* __restrict__ nnf, const float* __restrict__ ctx,
    const float* __restrict__ fc1w, const float* __restrict__ fc1b,
    const float* __restrict__ fc2w, const float* __restrict__ fc2b,
    float* __restrict__ attn, float* __restrict__ dfa) {
  int b = blockIdx.x;
  int t = threadIdx.x;  // 128 threads
  __shared__ float s_ctx[RH];
  __shared__ float s_v[NAV];
  __shared__ float s_hid[128];
  __shared__ float s_l[NF];
  __shared__ float s_inv[2];

  if (t < NAV) s_v[t] = nnf[b * NAV + t];
  for (int k = t; k < RH; k += 128) s_ctx[k] = ctx[b * RH + k];
  __syncthreads();

  if (t == 0) {
    float m = -1e30f;
    for (int i = 0; i < NAV; i++) m = fmaxf(m, s_v[i]);
    float s = 0.f;
    for (int i = 0; i < NAV; i++) { s_v[i] = expf(s_v[i] - m); s += s_v[i]; }
    s_inv[0] = 1.0f / s;
  }
  float acc = fc1b[t];
  const float* wr = fc1w + t * RH;
  for (int k = 0; k < RH; k++) acc += s_ctx[k] * wr[k];
  s_hid[t] = fmaxf(acc, 0.0f);
  __syncthreads();

  if (t < NAV) attn[b * NAV + t] = s_v[t] * s_inv[0];
  if (t < NF) {
    float a = fc2b[t];
    const float* w2 = fc2w + t * 128;
    for (int k = 0; k < 128; k++) a += s_hid[k] * w2[k];
    s_l[t] = a;
  }
  __syncthreads();
  if (t == 0) {
    float m = fmaxf(fmaxf(s_l[0], s_l[1]), fmaxf(s_l[2], s_l[3]));
    float s = 0.f;
    for (int f = 0; f < NF; f++) { s_l[f] = expf(s_l[f] - m); s += s_l[f]; }
    s_inv[1] = 1.0f / s;
  }
  __syncthreads();
  if (t < NF) dfa[b * NF + t] = s_l[t] * s_inv[1];
}

// ============ kernel 2: compose weights: C9 = kd_pd (*) W1, per (b,i) ============
__global__ __launch_bounds__(192) void k_comp(
    const float* __restrict__ c1w, const float* __restrict__ c1b,
    const float* __restrict__ dynf,
    const float* __restrict__ attn, const float* __restrict__ dfa,
    float* __restrict__ wsC) {
  int bi = blockIdx.x;
  int b = bi / NAV, i = bi - b * NAV;
  int t = threadIdx.x;
  __shared__ float s_kd[50];
  __shared__ float s_w1[50];
  if (t < 50) {
    float a = 0.f;
    for (int f = 0; f < NF; f++) a += dfa[b * NF + f] * dynf[(f * NAV + i) * 50 + t];
    s_kd[t] = a;
    s_w1[t] = c1w[i * 50 + t];
  }
  __syncthreads();
  float attn_bi = attn[bi];
  float* o = wsC + (size_t)bi * 240;
  if (t < 162) {
    int ch = t < 81 ? 0 : 1;
    int uv = t - 81 * ch;
    int u = uv / 9, v = uv - 9 * u;
    float c = 0.f;
    for (int a = 0; a < 5; a++) {
      int cc = u - a; if (cc < 0 || cc > 4) continue;
      for (int bb = 0; bb < 5; bb++) {
        int d = v - bb; if (d < 0 || d > 4) continue;
        c += s_kd[a * 5 + bb] * s_w1[ch * 25 + cc * 5 + d];
      }
    }
    o[ch * 81 + uv] = c * attn_bi;
  } else if (t < 187) {
    o[t] = s_kd[25 + (t - 162)] * attn_bi;   // attn*kd_po
  } else if (t == 187) {
    float s2 = 0.f;
    for (int j = 0; j < 25; j++) s2 += s_kd[j];
    o[187] = attn_bi * c1b[i] * s2;
  }
  if (t < 50) o[188 + t] = s_kd[t];
}

// ============ kernel 3: composed 9x9 conv -> compact pano (one tile/block) ============
// 3456 blocks = (b,i,seg) with seg = 0..5 covering 20 output rows each.
// Inner body identical to R18's proven tile; splitting the 3-tile persistent
// strip into one-tile blocks gives finer grid quantization (13.5 vs 4.5
// blocks/CU) and decorrelated barrier phases between resident blocks.
// LDW=168: f4-aligned, distinct row bank phase.
#define LDW 168
__global__ __launch_bounds__(512) void k_conv(
    const float* __restrict__ draw, const float* __restrict__ dclip,
    const float* __restrict__ obj,
    const float* __restrict__ wsC,
    float* __restrict__ cpano) {
  __shared__ __align__(16) float s_raw[24 * LDW];
  __shared__ __align__(16) float s_clip[24 * LDW];
  __shared__ __align__(16) float s_po[20 * LDW];
  __shared__ __align__(16) float s_part[1920];   // [part][160] float4
  __shared__ float s_C[188];

  int t = threadIdx.x;
  int bz = blockIdx.x;
  int pi = bz / 6;
  int seg = bz - 6 * pi;               // 0..5
  int b = pi / NAV, i = pi - b * NAV;
  int y0 = 20 * seg;

  const size_t plane = (size_t)pi * HIM * WIM;
  const float* rawp = draw + plane;
  const float* clipp = dclip + plane;
  const float* objp = obj + plane;
  int q = i / 12, cw = i - 12 * q;
  float* cpb = cpano + ((size_t)b * 72 + (2 - q) * 24) * 1920 + cw * WIM;

  // prologue: composed weights + halo-col zeros
  const float* cp = wsC + (size_t)pi * 240;
  if (t < 188) s_C[t] = cp[t];
  if (t < 384) {  // raw/clip: 2 arrays x 24 rows x 8 cols
    int ha = t < 192 ? 0 : 1, rem = t - 192 * ha;
    int r = rem >> 3, hc = rem & 7;
    int col = hc < 4 ? hc : 160 + hc;
    (ha ? s_clip : s_raw)[r * LDW + col] = 0.f;
  }
  if (t < 160) {  // po: 20 rows x 8 cols
    int r = t >> 3, hc = t & 7;
    int col = hc < 4 ? hc : 160 + hc;
    s_po[r * LDW + col] = 0.f;
  }

  // per-thread constant maps
  int prow[2], pg3[2]; bool pra[2];   // raw/clip: 960 f4 items = 24 rows x 40
#pragma unroll
  for (int jj = 0; jj < 2; jj++) {
    int idx = t + 512 * jj;
    pra[jj] = idx < 960;
    prow[jj] = idx / 40;
    pg3[jj] = idx - 40 * prow[jj];
  }
  int vrow[2], vg[2]; bool va[2];     // obj: 800 f4 items = 20 rows x 40
#pragma unroll
  for (int jj = 0; jj < 2; jj++) {
    int idx = t + 512 * jj;
    va[jj] = idx < 800;
    vrow[jj] = idx / 40;
    vg[jj] = idx - 40 * vrow[jj];
  }
  // compute map: part = t/160, pgc = t-160*part; row4 = pgc/40, gc = pgc%40
  int part = t / 160;                  // 0..2 active (t<480)
  int pgc = t - 160 * part;
  int row4 = pgc / 40;
  int gc = pgc - 40 * row4;
  int x0 = 4 * gc;
  int rbase = 5 * row4;
  bool cact = (t < 480);
  // reduce map (t<160)
  int rrow4 = t / 40;
  int rg = t - 40 * rrow4;

  // A: stage raw/clip/obj direct global->LDS (f4, 16B lane-stride)
  {
    float4 vr[2], vc[2], vo[2];
#pragma unroll
    for (int jj = 0; jj < 2; jj++) {
      int gy = y0 - 4 + prow[jj];
      bool ok = pra[jj] && gy >= 0 && gy < HIM;
      float4 a = {0.f, 0.f, 0.f, 0.f}, c = {0.f, 0.f, 0.f, 0.f};
      if (ok) { a = *(const float4*)(rawp + gy * WIM + 4 * pg3[jj]);
                c = *(const float4*)(clipp + gy * WIM + 4 * pg3[jj]); }
      vr[jj] = a; vc[jj] = c;
    }
#pragma unroll
    for (int jj = 0; jj < 2; jj++) {
      int gy = y0 - 2 + vrow[jj];
      float4 v = {0.f, 0.f, 0.f, 0.f};
      if (va[jj] && gy >= 0 && gy < HIM)
        v = *(const float4*)(objp + gy * WIM + 4 * vg[jj]);
      vo[jj] = v;
    }
#pragma unroll
    for (int jj = 0; jj < 2; jj++) {
      if (pra[jj]) {
        *(float4*)&s_raw[prow[jj] * LDW + 4 + 4 * pg3[jj]] = vr[jj];
        *(float4*)&s_clip[prow[jj] * LDW + 4 + 4 * pg3[jj]] = vc[jj];
      }
    }
#pragma unroll
    for (int jj = 0; jj < 2; jj++) {
      if (va[jj]) *(float4*)&s_po[vrow[jj] * LDW + 4 + 4 * vg[jj]] = vo[jj];
    }
  }
  __syncthreads();

  // B: partial compute (480 threads): 3 u-rows + share of po rows
  if (cact) {
    float a0 = 0.f, a1 = 0.f, a2 = 0.f, a3 = 0.f;
    int ub = rbase + 3 * part;
#pragma unroll
    for (int u = 0; u < 3; u++) {
      const float* rp = &s_raw[(ub + u) * LDW + x0];
      const float* cl = &s_clip[(ub + u) * LDW + x0];
      float rw[12], cc[12];
      *(float4*)&rw[0] = *(const float4*)rp;
      *(float4*)&rw[4] = *(const float4*)(rp + 4);
      *(float4*)&rw[8] = *(const float4*)(rp + 8);
      *(float4*)&cc[0] = *(const float4*)cl;
      *(float4*)&cc[4] = *(const float4*)(cl + 4);
      *(float4*)&cc[8] = *(const float4*)(cl + 8);
      const float* Cr = &s_C[(3 * part + u) * 9];
#pragma unroll
      for (int v = 0; v < 9; v++) {
        float wr = Cr[v], wc = Cr[81 + v];
        a0 += rw[v] * wr + cc[v] * wc;
        a1 += rw[v + 1] * wr + cc[v + 1] * wc;
        a2 += rw[v + 2] * wr + cc[v + 2] * wc;
        a3 += rw[v + 3] * wr + cc[v + 3] * wc;
      }
    }
    int ndd = (part == 2) ? 1 : 2;
    int dd0 = 2 * part;
    for (int dd = 0; dd < ndd; dd++) {
      int dr = dd0 + dd;
      const float* pp = &s_po[(rbase + dr) * LDW + x0];
      float po[12];
      *(float4*)&po[0] = *(const float4*)pp;
      *(float4*)&po[4] = *(const float4*)(pp + 4);
      *(float4*)&po[8] = *(const float4*)(pp + 8);
      const float* Cp = &s_C[162 + dr * 5];
#pragma unroll
      for (int d = 0; d < 5; d++) {
        float w = Cp[d];
        a0 += po[d + 2] * w;
        a1 += po[d + 3] * w;
        a2 += po[d + 4] * w;
        a3 += po[d + 5] * w;
      }
    }
    float4 p4 = {a0, a1, a2, a3};
    *(float4*)&s_part[t * 4] = p4;
  }
  __syncthreads();

  // C: reduce partials + store (160 threads)
  if (t < 160) {
    float4 p0 = *(const float4*)&s_part[(0 * 160 + t) * 4];
    float4 p1 = *(const float4*)&s_part[(1 * 160 + t) * 4];
    float4 p2 = *(const float4*)&s_part[(2 * 160 + t) * 4];
    float c187 = s_C[187];
    float a0 = p0.x + p1.x + p2.x + c187;
    float a1 = p0.y + p1.y + p2.y + c187;
    float a2 = p0.z + p1.z + p2.z + c187;
    float a3 = p0.w + p1.w + p2.w + c187;
    int y = y0 + 5 * rrow4;
    if (y != 0) {
      float* op = cpb + (size_t)(4 * seg + rrow4) * 1920 + 4 * rg;
      if (rg == 0) { op[2] = a2; op[3] = a3; }
      else if (rg == 39) { op[0] = a0; op[1] = a1; }
      else { float4 o4 = {a0, a1, a2, a3}; *(float4*)op = o4; }
    }
  }
}

// ============ kernel 4: boundary fixup — strip-staged, balanced (R11-proven) ============
__global__ __launch_bounds__(256) void k_fix(
    const float* __restrict__ draw, const float* __restrict__ dclip,
    const float* __restrict__ obj,
    const float* __restrict__ c1w, const float* __restrict__ c1b,
    const float* __restrict__ attn, const float* __restrict__ wsC,
    float* __restrict__ cpano) {
  __shared__ float s_top[2][5][168];
  __shared__ float s_L[2][120][13];
  __shared__ float s_R[2][120][13];
  __shared__ float s_pdt[3][168];
  __shared__ float s_pdL[4][120];
  __shared__ float s_pdR[4][120];
  __shared__ float s_w1[50], s_kd[50];

  int bi = blockIdx.x;
  int b = bi / NAV, i = bi - b * NAV;
  int t = threadIdx.x;
  const size_t plane = (size_t)bi * HIM * WIM;
  const float* rawp = draw + plane;
  const float* clipp = dclip + plane;
  const float* objp = obj + plane;
  float attn_bi = attn[bi];
  float bias = c1b[i];

  if (t < 50) { s_w1[t] = c1w[i * 50 + t]; s_kd[t] = wsC[(size_t)bi * 240 + 188 + t]; }
  if (t < 80) { int a = t / 40, rem = t - 40 * a; int r = rem / 8, hc = rem & 7;
    s_top[a][r][hc < 4 ? hc : 160 + hc] = 0.f; }
  else if (t < 104) { int rem = t - 80; int r = rem / 8, hc = rem & 7;
    s_pdt[r][hc < 4 ? hc : 160 + hc] = 0.f; }
  for (int it = t; it < 2 * 2 * 120 * 7; it += 256) {
    int side = it / 1680, rem = it - 1680 * side;
    int a = rem / 840; rem -= 840 * a;
    int row = rem / 7, jj = rem - 7 * row;
    if (side == 0) s_L[a][row][jj < 2 ? jj : 6 + jj] = 0.f;
    else           s_R[a][row][6 + jj] = 0.f;
  }
  for (int it = t; it < 400; it += 256) {
    int a = it / 200, rem = it - 200 * a;
    int r = rem / 40, g = rem - 40 * r;
    const float* src = a ? clipp : rawp;
    *(float4*)&s_top[a][r][4 + 4 * g] = *(const float4*)(src + r * WIM + 4 * g);
  }
  for (int it = t; it < 2 * 2 * 120 * 6; it += 256) {
    int side = it / 1440, rem = it - 1440 * side;
    int a = rem / 720; rem -= 720 * a;
    int row = rem / 6, c = rem - 6 * row;
    const float* src = a ? clipp : rawp;
    if (side == 0) s_L[a][row][2 + c] = src[row * WIM + c];
    else           s_R[a][row][c] = src[row * WIM + 154 + c];
  }
  __syncthreads();

  for (int it = t; it < 480; it += 256) {
    int r = it / 160, x = it - 160 * r;
    float v = 0.f;
#pragma unroll
    for (int c = 0; c < 5; c++) {
      int rr = r - 2 + c;
      if (rr >= 0) {
#pragma unroll
        for (int d = 0; d < 5; d++) {
          int j = 2 + x + d;
          v += s_w1[c * 5 + d] * s_top[0][rr][j] + s_w1[25 + c * 5 + d] * s_top[1][rr][j];
        }
      }
    }
    s_pdt[r][4 + x] = bias + v;
  }
  for (int it = t; it < 460; it += 256) {
    int c = it / 115, y = 3 + (it - 115 * c);
    float v = 0.f;
#pragma unroll
    for (int cp = 0; cp < 5; cp++) {
      int rr = y - 2 + cp;
#pragma unroll
      for (int d = 0; d < 5; d++)
        v += s_w1[cp * 5 + d] * s_L[0][rr][c + d] + s_w1[25 + cp * 5 + d] * s_L[1][rr][c + d];
    }
    s_pdL[c][y] = bias + v;
  }
  for (int it = t; it < 460; it += 256) {
    int c = it / 115, y = 3 + (it - 115 * c);
    float v = 0.f;
#pragma unroll
    for (int cp = 0; cp < 5; cp++) {
      int rr = y - 2 + cp;
#pragma unroll
      for (int d = 0; d < 5; d++)
        v += s_w1[cp * 5 + d] * s_R[0][rr][c + d] + s_w1[25 + cp * 5 + d] * s_R[1][rr][c + d];
    }
    s_pdR[c][y] = bias + v;
  }
  __syncthreads();

  if (t < 252) {
    int y, x;
    if (t < 160) { y = 0; x = t; }
    else {
      int k = t - 160;
      int ri = k >> 2, xi = k & 3;
      y = 5 * (ri + 1);
      x = xi < 2 ? xi : 156 + xi;
    }
    float acc = 0.f;
    if (y == 0) {
#pragma unroll
      for (int a = 2; a < 5; a++)
#pragma unroll
        for (int bb2 = 0; bb2 < 5; bb2++)
          acc += s_kd[a * 5 + bb2] * s_pdt[a - 2][2 + x + bb2];
    } else {
#pragma unroll
      for (int a = 0; a < 5; a++) {
        int ry = y + a - 2;
#pragma unroll
        for (int bb2 = 0; bb2 < 5; bb2++) {
          int q = x + bb2 - 2;
          if (q < 0 || q >= 160) continue;
          float pdv = (q < 4) ? s_pdL[q][ry] : s_pdR[q - 156][ry];
          acc += s_kd[a * 5 + bb2] * pdv;
        }
      }
    }
#pragma unroll
    for (int dd = 0; dd < 5; dd++) {
      int ry = y + dd - 2;
      if (ry < 0 || ry >= HIM) continue;
#pragma unroll
      for (int d = 0; d < 5; d++) {
        int rx = x + d - 2;
        if (rx < 0 || rx >= WIM) continue;
        acc += s_kd[25 + dd * 5 + d] * objp[ry * WIM + rx];
      }
    }
    acc *= attn_bi;
    int q2 = i / 12, cw = i - 12 * q2;
    cpano[((size_t)b * 72 + (2 - q2) * 24 + y / 5) * 1920 + cw * WIM + x] = acc;
  }
}

// ============ kernel 5: conv2_1 on compact pano, both roll paths ============
__global__ __launch_bounds__(256) void k_c21(
    const float* __restrict__ cpano, const float* __restrict__ w21,
    const float* __restrict__ b21, float* __restrict__ y1) {
  __shared__ float s_rows[5][1920];
  int t = threadIdx.x;
  int b = blockIdx.x, oy = blockIdx.y;
  const float* pp = cpano + (size_t)b * 72 * 1920;
  for (int tt = t; tt < 2400; tt += 256) {
    int ky = tt / 480, g = tt - 480 * ky;
    *(float4*)&s_rows[ky][4 * g] = *(const float4*)&pp[(size_t)(oy + 2 * ky) * 1920 + 4 * g];
  }
  float w[25];
#pragma unroll
  for (int k = 0; k < 25; k++) w[k] = w21[k];
  float bb = b21[0];
  __syncthreads();
  for (int tt = t; tt < 538; tt += 256) {
    int p = tt / 269, ox = tt - 269 * p;
    int shift = p ? 1760 : 0;
    float acc = bb;
#pragma unroll
    for (int ky = 0; ky < 5; ky++)
#pragma unroll
      for (int kx = 0; kx < 5; kx++) {
        int X = 7 * ox + 10 * kx + shift;
        if (X >= 1920) X -= 1920;
        acc += w[ky * 5 + kx] * s_rows[ky][X];
      }
    y1[((size_t)(p * B + b) * 64 + oy) * 269 + ox] = acc;
  }
}

// ============ kernel 6: fused pools+conv2_2 (both paths) + vf softmax ============
__global__ __launch_bounds__(512) void k_tailvf(
    const float* __restrict__ y1, const float* __restrict__ w22,
    const float* __restrict__ b22, const int* __restrict__ nav_idx,
    float* __restrict__ out_vf, float* __restrict__ out_mask) {
  __shared__ float s_y2[2][21][90];
  __shared__ float s_y3[2][10][44];
  __shared__ float s_vf2[2][36];
  __shared__ float s_v[36];
  __shared__ float s_inv;
  int t = threadIdx.x;
  int b = blockIdx.x;
  int p = t >> 8, tp = t & 255;
  const float* yp = y1 + (size_t)(p * B + b) * 64 * 269;
  for (int idx = tp; idx < 21 * 89; idx += 256) {
    int py = idx / 89, px = idx - 89 * py;
    float s = 0.f;
    for (int dy = 0; dy < 3; dy++)
      for (int dx = 0; dx < 3; dx++)
        s += yp[(3 * py + dy) * 269 + 3 * px + dx];
    s_y2[p][py][px] = s * (1.0f / 9.0f);
  }
  __syncthreads();
  for (int idx = tp; idx < 10 * 43; idx += 256) {
    int qy = idx / 43, qx = idx - 43 * qy;
    float a = b22[0];
#pragma unroll
    for (int ky = 0; ky < 3; ky++)
#pragma unroll
      for (int kx = 0; kx < 3; kx++)
        a += w22[ky * 3 + kx] * s_y2[p][2 * qy + ky][2 * qx + 2 * kx];
    s_y3[p][qy][qx] = a;
  }
  __syncthreads();
  if (tp < 36) {
    int uy = tp / 12, ux = tp - 12 * uy;
    float s = 0.f;
    for (int dy = 0; dy < 3; dy++)
      for (int dx = 0; dx < 9; dx++)
        s += s_y3[p][3 * uy + dy][3 * ux + dx];
    s_vf2[p][tp] = s * (1.0f / 27.0f);
  }
  __syncthreads();
  if (t < 36) {
    int u = t / 12, x = t - 12 * u;
    float v1 = s_vf2[0][(2 - u) * 12 + x];
    float v2 = s_vf2[1][(2 - u) * 12 + (x + 1) % 12];
    s_v[t] = 0.5f * (v1 + v2) * 0.1f;
  }
  __syncthreads();
  if (t == 0) {
    float m = -1e30f;
    for (int i = 0; i < 36; i++) m = fmaxf(m, s_v[i]);
    float s = 0.f;
    for (int i = 0; i < 36; i++) { s_v[i] = expf(s_v[i] - m); s += s_v[i]; }
    s_inv = 1.0f / s;
  }
  __syncthreads();
  if (t < 36) {
    out_vf[b * 36 + t] = s_v[t] * s_inv;
    float m = 0.f;
    for (int e = 0; e < 8; e++)
      if (nav_idx[b * 8 + e] == t) m = 1.0f;
    out_mask[b * 36 + t] = m;
  }
}

// ============ kernel 7: LSTM, 512 blocks (1 unit each), f4 weight loads ============
__global__ __launch_bounds__(256) void k_lstm(
    const float* __restrict__ ctx, const float* __restrict__ vf,
    const float* __restrict__ dfa, const float* __restrict__ pre,
    const float* __restrict__ h0, const float* __restrict__ c0,
    const float* __restrict__ wih, const float* __restrict__ whh,
    const float* __restrict__ bih, const float* __restrict__ bhh,
    float* __restrict__ h1, float* __restrict__ c1) {
  __shared__ float s_cat[B][1104];   // [0,589) cat, [592,1104) h0
  __shared__ float s_g[4][16];
  int t = threadIdx.x;
  int u = blockIdx.x;
  int g = t >> 6, l = t & 63;
  for (int idx = t; idx < B * 589; idx += 256) {
    int b = idx / 589, k = idx - 589 * b;
    float v;
    if (k < 512) v = ctx[b * 512 + k];
    else if (k < 548) v = vf[b * 36 + (k - 512)];
    else if (k < 552) v = dfa[b * 4 + (k - 548)];
    else v = pre[b * 37 + (k - 552)];
    s_cat[b][k] = v;
  }
  for (int idx = t; idx < B * 512; idx += 256) {
    int b = idx >> 9, k = idx & 511;
    s_cat[b][592 + k] = h0[b * 512 + k];
  }
  __syncthreads();
  int j = (g << 9) + u;
  float acc[B];
#pragma unroll
  for (int b = 0; b < B; b++) acc[b] = 0.f;
  const float* wi = wih + (size_t)j * 589;
#pragma unroll
  for (int it = 0; it < 3; it++) {
    int c = l + 64 * it;
    if (c < 147) {
      int k = 4 * c;
      float w0 = wi[k], w1 = wi[k + 1], w2 = wi[k + 2], w3 = wi[k + 3];
#pragma unroll
      for (int b = 0; b < B; b++) {
        float4 cc = *(const float4*)&s_cat[b][k];
        acc[b] += cc.x * w0 + cc.y * w1 + cc.z * w2 + cc.w * w3;
      }
    }
  }
  if (l == 0) {
    float w = wi[588];
#pragma unroll
    for (int b = 0; b < B; b++) acc[b] += w * s_cat[b][588];
  }
  const float* wh = whh + (size_t)j * 512;
#pragma unroll
  for (int it = 0; it < 2; it++) {
    int k = 4 * (l + 64 * it);
    float4 w4 = *(const float4*)&wh[k];
#pragma unroll
    for (int b = 0; b < B; b++) {
      float4 cc = *(const float4*)&s_cat[b][592 + k];
      acc[b] += cc.x * w4.x + cc.y * w4.y + cc.z * w4.z + cc.w * w4.w;
    }
  }
#pragma unroll
  for (int off = 1; off < 64; off <<= 1)
#pragma unroll
    for (int b = 0; b < B; b++) acc[b] += __shfl_xor(acc[b], off);
  if (l == 0) {
    float bb = bih[j] + bhh[j];
#pragma unroll
    for (int b = 0; b < B; b++) s_g[g][b] = acc[b] + bb;
  }
  __syncthreads();
  if (t < 16) {
    float gi = s_g[0][t], gf = s_g[1][t], gg = s_g[2][t], go = s_g[3][t];
    float c_old = c0[t * 512 + u];
    float si = 1.0f / (1.0f + expf(-gi));
    float sf = 1.0f / (1.0f + expf(-gf));
    float so = 1.0f / (1.0f + expf(-go));
    float cn = sf * c_old + si * tanhf(gg);
    h1[t * 512 + u] = so * tanhf(cn);
    c1[t * 512 + u] = cn;
  }
}

extern "C" void kernel_launch(void* const* d_in, const int* in_sizes, int n_in,
                              void* d_out, int out_size, void* d_ws, size_t ws_size,
                              hipStream_t stream) {
  const float* depth_raw  = (const float*)d_in[0];
  const float* depth_clip = (const float*)d_in[1];
  const float* obj_feat   = (const float*)d_in[2];
  const float* nnf        = (const float*)d_in[3];
  const float* pre        = (const float*)d_in[4];
  const float* h0         = (const float*)d_in[5];
  const float* c0         = (const float*)d_in[6];
  const float* ctx        = (const float*)d_in[7];
  const int*   nav_idx    = (const int*)d_in[8];
  const float* c1w        = (const float*)d_in[9];
  const float* c1b        = (const float*)d_in[10];
  const float* fc1w       = (const float*)d_in[11];
  const float* fc1b       = (const float*)d_in[12];
  const float* fc2w       = (const float*)d_in[13];
  const float* fc2b       = (const float*)d_in[14];
  const float* dynf       = (const float*)d_in[15];
  const float* w21        = (const float*)d_in[16];
  const float* b21        = (const float*)d_in[17];
  const float* w22        = (const float*)d_in[18];
  const float* b22        = (const float*)d_in[19];
  const float* wih        = (const float*)d_in[20];
  const float* whh        = (const float*)d_in[21];
  const float* bih        = (const float*)d_in[22];
  const float* bhh        = (const float*)d_in[23];

  float* ws = (float*)d_ws;
  float* attn   = ws;
  float* dfa    = ws + 576;
  float* y1     = ws + 1792;
  float* cpano  = ws + 552704;
  float* wsC    = ws + 2764544;

  float* out = (float*)d_out;
  float* out_h1   = out;
  float* out_c1   = out + 8192;
  float* out_vf   = out + 16384;
  float* out_mask = out + 16960;

  k_head<<<B, 128, 0, stream>>>(nnf, ctx, fc1w, fc1b, fc2w, fc2b, attn, dfa);
  k_comp<<<B * NAV, 192, 0, stream>>>(c1w, c1b, dynf, attn, dfa, wsC);
  k_conv<<<B * NAV * 6, 512, 0, stream>>>(depth_raw, depth_clip, obj_feat, wsC, cpano);
  k_fix<<<B * NAV, 256, 0, stream>>>(depth_raw, depth_clip, obj_feat,
                                     c1w, c1b, attn, wsC, cpano);
  k_c21<<<dim3(B, 64), 256, 0, stream>>>(cpano, w21, b21, y1);
  k_tailvf<<<B, 512, 0, stream>>>(y1, w22, b22, nav_idx, out_vf, out_mask);
  k_lstm<<<RH, 256, 0, stream>>>(ctx, out_vf, dfa, pre, h0, c0,
                                 wih, whh, bih, bhh, out_h1, out_c1);
}

// Round 22
// 116.193 us; speedup vs baseline: 1.1437x; 1.0168x over previous
//
#include <hip/hip_runtime.h>
#include <math.h>

#define B 16
#define NAV 36
#define HIM 120
#define WIM 160
#define RH 512
#define NF 4
#define AE 37

// ---------------- workspace layout (floats) ----------------
// attn   : [B*NAV]            @ 0        (576)
// dfa    : [B*NF]             @ 576      (64)
// y1     : [2][B][64][269]    @ 1792     (550912)
// cpano  : [B][72][1920]      @ 552704   (2211840)
// wsC    : [576][240]         @ 2764544  (138240)

// ============ kernel 1: attn softmax + dynamic-filter MLP ============
__global__ __launch_bounds__(128) void k_head(
    const float* __restrict__ nnf, const float* __restrict__ ctx,
    const float* __restrict__ fc1w, const float* __restrict__ fc1b,
    const float* __restrict__ fc2w, const float* __restrict__ fc2b,
    float* __restrict__ attn, float* __restrict__ dfa) {
  int b = blockIdx.x;
  int t = threadIdx.x;  // 128 threads
  __shared__ float s_ctx[RH];
  __shared__ float s_v[NAV];
  __shared__ float s_hid[128];
  __shared__ float s_l[NF];
  __shared__ float s_inv[2];

  if (t < NAV) s_v[t] = nnf[b * NAV + t];
  for (int k = t; k < RH; k += 128) s_ctx[k] = ctx[b * RH + k];
  __syncthreads();

  if (t == 0) {
    float m = -1e30f;
    for (int i = 0; i < NAV; i++) m = fmaxf(m, s_v[i]);
    float s = 0.f;
    for (int i = 0; i < NAV; i++) { s_v[i] = expf(s_v[i] - m); s += s_v[i]; }
    s_inv[0] = 1.0f / s;
  }
  float acc = fc1b[t];
  const float* wr = fc1w + t * RH;
  for (int k = 0; k < RH; k++) acc += s_ctx[k] * wr[k];
  s_hid[t] = fmaxf(acc, 0.0f);
  __syncthreads();

  if (t < NAV) attn[b * NAV + t] = s_v[t] * s_inv[0];
  if (t < NF) {
    float a = fc2b[t];
    const float* w2 = fc2w + t * 128;
    for (int k = 0; k < 128; k++) a += s_hid[k] * w2[k];
    s_l[t] = a;
  }
  __syncthreads();
  if (t == 0) {
    float m = fmaxf(fmaxf(s_l[0], s_l[1]), fmaxf(s_l[2], s_l[3]));
    float s = 0.f;
    for (int f = 0; f < NF; f++) { s_l[f] = expf(s_l[f] - m); s += s_l[f]; }
    s_inv[1] = 1.0f / s;
  }
  __syncthreads();
  if (t < NF) dfa[b * NF + t] = s_l[t] * s_inv[1];
}

// ============ kernel 2: compose weights: C9 = kd_pd (*) W1, per (b,i) ============
__global__ __launch_bounds__(192) void k_comp(
    const float* __restrict__ c1w, const float* __restrict__ c1b,
    const float* __restrict__ dynf,
    const float* __restrict__ attn, const float* __restrict__ dfa,
    float* __restrict__ wsC) {
  int bi = blockIdx.x;
  int b = bi / NAV, i = bi - b * NAV;
  int t = threadIdx.x;
  __shared__ float s_kd[50];
  __shared__ float s_w1[50];
  if (t < 50) {
    float a = 0.f;
    for (int f = 0; f < NF; f++) a += dfa[b * NF + f] * dynf[(f * NAV + i) * 50 + t];
    s_kd[t] = a;
    s_w1[t] = c1w[i * 50 + t];
  }
  __syncthreads();
  float attn_bi = attn[bi];
  float* o = wsC + (size_t)bi * 240;
  if (t < 162) {
    int ch = t < 81 ? 0 : 1;
    int uv = t - 81 * ch;
    int u = uv / 9, v = uv - 9 * u;
    float c = 0.f;
    for (int a = 0; a < 5; a++) {
      int cc = u - a; if (cc < 0 || cc > 4) continue;
      for (int bb = 0; bb < 5; bb++) {
        int d = v - bb; if (d < 0 || d > 4) continue;
        c += s_kd[a * 5 + bb] * s_w1[ch * 25 + cc * 5 + d];
      }
    }
    o[ch * 81 + uv] = c * attn_bi;
  } else if (t < 187) {
    o[t] = s_kd[25 + (t - 162)] * attn_bi;   // attn*kd_po
  } else if (t == 187) {
    float s2 = 0.f;
    for (int j = 0; j < 25; j++) s2 += s_kd[j];
    o[187] = attn_bi * c1b[i] * s2;
  }
  if (t < 50) o[188 + t] = s_kd[t];
}

// ============ kernel 3: composed 9x9 conv -> compact pano (10-row tiles) ============
// 6912 blocks = (b,i,seg), seg=0..11 covering 10 output rows each (2 out
// rows y0, y0+5). 256 threads: stage 14 raw/clip + 10 po rows; compute 240
// threads (3 parts x 2 rows x 40 groups); reduce+store with 80.
// LDS 30.1KB -> 5 blocks/CU (20 waves); grid 27 blocks/CU.
#define LDW 168
__global__ __launch_bounds__(256) void k_conv(
    const float* __restrict__ draw, const float* __restrict__ dclip,
    const float* __restrict__ obj,
    const float* __restrict__ wsC,
    float* __restrict__ cpano) {
  __shared__ __align__(16) float s_raw[14 * LDW];
  __shared__ __align__(16) float s_clip[14 * LDW];
  __shared__ __align__(16) float s_po[10 * LDW];
  __shared__ __align__(16) float s_part[960];   // [part][80] float4
  __shared__ float s_C[188];

  int t = threadIdx.x;
  int bz = blockIdx.x;
  int pi = bz / 12;
  int seg = bz - 12 * pi;              // 0..11
  int b = pi / NAV, i = pi - b * NAV;
  int y0 = 10 * seg;

  const size_t plane = (size_t)pi * HIM * WIM;
  const float* rawp = draw + plane;
  const float* clipp = dclip + plane;
  const float* objp = obj + plane;
  int q = i / 12, cw = i - 12 * q;
  float* cpb = cpano + ((size_t)b * 72 + (2 - q) * 24) * 1920 + cw * WIM;

  // prologue: composed weights + halo-col zeros
  const float* cp = wsC + (size_t)pi * 240;
  if (t < 188) s_C[t] = cp[t];
  if (t < 224) {  // raw/clip: 2 arrays x 14 rows x 8 cols
    int ha = t < 112 ? 0 : 1, rem = t - 112 * ha;
    int r = rem >> 3, hc = rem & 7;
    int col = hc < 4 ? hc : 160 + hc;
    (ha ? s_clip : s_raw)[r * LDW + col] = 0.f;
  }
  if (t < 80) {   // po: 10 rows x 8 cols
    int r = t >> 3, hc = t & 7;
    int col = hc < 4 ? hc : 160 + hc;
    s_po[r * LDW + col] = 0.f;
  }

  // per-thread constant maps
  int prow[3], pg3[3]; bool pra[3];   // raw/clip: 560 f4 items = 14 rows x 40
#pragma unroll
  for (int jj = 0; jj < 3; jj++) {
    int idx = t + 256 * jj;
    pra[jj] = idx < 560;
    prow[jj] = idx / 40;
    pg3[jj] = idx - 40 * prow[jj];
  }
  int vrow[2], vg[2]; bool va[2];     // obj: 400 f4 items = 10 rows x 40
#pragma unroll
  for (int jj = 0; jj < 2; jj++) {
    int idx = t + 256 * jj;
    va[jj] = idx < 400;
    vrow[jj] = idx / 40;
    vg[jj] = idx - 40 * vrow[jj];
  }
  // compute map: part = t/80 (0..2 active), pgc = t-80*part; row2 = pgc/40
  int part = t / 80;
  int pgc = t - 80 * part;
  int row2 = pgc / 40;
  int gc = pgc - 40 * row2;
  int x0 = 4 * gc;
  int rbase = 5 * row2;
  bool cact = (t < 240);
  // reduce map (t<80)
  int rrow2 = t / 40;
  int rg = t - 40 * rrow2;

  // A: stage raw/clip/obj direct global->LDS (f4, 16B lane-stride)
  {
    float4 vr[3], vc[3], vo[2];
#pragma unroll
    for (int jj = 0; jj < 3; jj++) {
      int gy = y0 - 4 + prow[jj];
      bool ok = pra[jj] && gy >= 0 && gy < HIM;
      float4 a = {0.f, 0.f, 0.f, 0.f}, c = {0.f, 0.f, 0.f, 0.f};
      if (ok) { a = *(const float4*)(rawp + gy * WIM + 4 * pg3[jj]);
                c = *(const float4*)(clipp + gy * WIM + 4 * pg3[jj]); }
      vr[jj] = a; vc[jj] = c;
    }
#pragma unroll
    for (int jj = 0; jj < 2; jj++) {
      int gy = y0 - 2 + vrow[jj];
      float4 v = {0.f, 0.f, 0.f, 0.f};
      if (va[jj] && gy >= 0 && gy < HIM)
        v = *(const float4*)(objp + gy * WIM + 4 * vg[jj]);
      vo[jj] = v;
    }
#pragma unroll
    for (int jj = 0; jj < 3; jj++) {
      if (pra[jj]) {
        *(float4*)&s_raw[prow[jj] * LDW + 4 + 4 * pg3[jj]] = vr[jj];
        *(float4*)&s_clip[prow[jj] * LDW + 4 + 4 * pg3[jj]] = vc[jj];
      }
    }
#pragma unroll
    for (int jj = 0; jj < 2; jj++) {
      if (va[jj]) *(float4*)&s_po[vrow[jj] * LDW + 4 + 4 * vg[jj]] = vo[jj];
    }
  }
  __syncthreads();

  // B: partial compute (240 threads): 3 u-rows + share of po rows
  if (cact) {
    float a0 = 0.f, a1 = 0.f, a2 = 0.f, a3 = 0.f;
    int ub = rbase + 3 * part;
#pragma unroll
    for (int u = 0; u < 3; u++) {
      const float* rp = &s_raw[(ub + u) * LDW + x0];
      const float* cl = &s_clip[(ub + u) * LDW + x0];
      float rw[12], cc[12];
      *(float4*)&rw[0] = *(const float4*)rp;
      *(float4*)&rw[4] = *(const float4*)(rp + 4);
      *(float4*)&rw[8] = *(const float4*)(rp + 8);
      *(float4*)&cc[0] = *(const float4*)cl;
      *(float4*)&cc[4] = *(const float4*)(cl + 4);
      *(float4*)&cc[8] = *(const float4*)(cl + 8);
      const float* Cr = &s_C[(3 * part + u) * 9];
#pragma unroll
      for (int v = 0; v < 9; v++) {
        float wr = Cr[v], wc = Cr[81 + v];
        a0 += rw[v] * wr + cc[v] * wc;
        a1 += rw[v + 1] * wr + cc[v + 1] * wc;
        a2 += rw[v + 2] * wr + cc[v + 2] * wc;
        a3 += rw[v + 3] * wr + cc[v + 3] * wc;
      }
    }
    int ndd = (part == 2) ? 1 : 2;
    int dd0 = 2 * part;
    for (int dd = 0; dd < ndd; dd++) {
      int dr = dd0 + dd;
      const float* pp = &s_po[(rbase + dr) * LDW + x0];
      float po[12];
      *(float4*)&po[0] = *(const float4*)pp;
      *(float4*)&po[4] = *(const float4*)(pp + 4);
      *(float4*)&po[8] = *(const float4*)(pp + 8);
      const float* Cp = &s_C[162 + dr * 5];
#pragma unroll
      for (int d = 0; d < 5; d++) {
        float w = Cp[d];
        a0 += po[d + 2] * w;
        a1 += po[d + 3] * w;
        a2 += po[d + 4] * w;
        a3 += po[d + 5] * w;
      }
    }
    float4 p4 = {a0, a1, a2, a3};
    *(float4*)&s_part[t * 4] = p4;
  }
  __syncthreads();

  // C: reduce partials + store (80 threads)
  if (t < 80) {
    float4 p0 = *(const float4*)&s_part[(0 * 80 + t) * 4];
    float4 p1 = *(const float4*)&s_part[(1 * 80 + t) * 4];
    float4 p2 = *(const float4*)&s_part[(2 * 80 + t) * 4];
    float c187 = s_C[187];
    float a0 = p0.x + p1.x + p2.x + c187;
    float a1 = p0.y + p1.y + p2.y + c187;
    float a2 = p0.z + p1.z + p2.z + c187;
    float a3 = p0.w + p1.w + p2.w + c187;
    int y = y0 + 5 * rrow2;
    if (y != 0) {
      float* op = cpb + (size_t)(2 * seg + rrow2) * 1920 + 4 * rg;
      if (rg == 0) { op[2] = a2; op[3] = a3; }
      else if (rg == 39) { op[0] = a0; op[1] = a1; }
      else { float4 o4 = {a0, a1, a2, a3}; *(float4*)op = o4; }
    }
  }
}

// ============ kernel 4: boundary fixup — strip-staged, balanced (R11-proven) ============
__global__ __launch_bounds__(256) void k_fix(
    const float* __restrict__ draw, const float* __restrict__ dclip,
    const float* __restrict__ obj,
    const float* __restrict__ c1w, const float* __restrict__ c1b,
    const float* __restrict__ attn, const float* __restrict__ wsC,
    float* __restrict__ cpano) {
  __shared__ float s_top[2][5][168];
  __shared__ float s_L[2][120][13];
  __shared__ float s_R[2][120][13];
  __shared__ float s_pdt[3][168];
  __shared__ float s_pdL[4][120];
  __shared__ float s_pdR[4][120];
  __shared__ float s_w1[50], s_kd[50];

  int bi = blockIdx.x;
  int b = bi / NAV, i = bi - b * NAV;
  int t = threadIdx.x;
  const size_t plane = (size_t)bi * HIM * WIM;
  const float* rawp = draw + plane;
  const float* clipp = dclip + plane;
  const float* objp = obj + plane;
  float attn_bi = attn[bi];
  float bias = c1b[i];

  if (t < 50) { s_w1[t] = c1w[i * 50 + t]; s_kd[t] = wsC[(size_t)bi * 240 + 188 + t]; }
  if (t < 80) { int a = t / 40, rem = t - 40 * a; int r = rem / 8, hc = rem & 7;
    s_top[a][r][hc < 4 ? hc : 160 + hc] = 0.f; }
  else if (t < 104) { int rem = t - 80; int r = rem / 8, hc = rem & 7;
    s_pdt[r][hc < 4 ? hc : 160 + hc] = 0.f; }
  for (int it = t; it < 2 * 2 * 120 * 7; it += 256) {
    int side = it / 1680, rem = it - 1680 * side;
    int a = rem / 840; rem -= 840 * a;
    int row = rem / 7, jj = rem - 7 * row;
    if (side == 0) s_L[a][row][jj < 2 ? jj : 6 + jj] = 0.f;
    else           s_R[a][row][6 + jj] = 0.f;
  }
  for (int it = t; it < 400; it += 256) {
    int a = it / 200, rem = it - 200 * a;
    int r = rem / 40, g = rem - 40 * r;
    const float* src = a ? clipp : rawp;
    *(float4*)&s_top[a][r][4 + 4 * g] = *(const float4*)(src + r * WIM + 4 * g);
  }
  for (int it = t; it < 2 * 2 * 120 * 6; it += 256) {
    int side = it / 1440, rem = it - 1440 * side;
    int a = rem / 720; rem -= 720 * a;
    int row = rem / 6, c = rem - 6 * row;
    const float* src = a ? clipp : rawp;
    if (side == 0) s_L[a][row][2 + c] = src[row * WIM + c];
    else           s_R[a][row][c] = src[row * WIM + 154 + c];
  }
  __syncthreads();

  for (int it = t; it < 480; it += 256) {
    int r = it / 160, x = it - 160 * r;
    float v = 0.f;
#pragma unroll
    for (int c = 0; c < 5; c++) {
      int rr = r - 2 + c;
      if (rr >= 0) {
#pragma unroll
        for (int d = 0; d < 5; d++) {
          int j = 2 + x + d;
          v += s_w1[c * 5 + d] * s_top[0][rr][j] + s_w1[25 + c * 5 + d] * s_top[1][rr][j];
        }
      }
    }
    s_pdt[r][4 + x] = bias + v;
  }
  for (int it = t; it < 460; it += 256) {
    int c = it / 115, y = 3 + (it - 115 * c);
    float v = 0.f;
#pragma unroll
    for (int cp = 0; cp < 5; cp++) {
      int rr = y - 2 + cp;
#pragma unroll
      for (int d = 0; d < 5; d++)
        v += s_w1[cp * 5 + d] * s_L[0][rr][c + d] + s_w1[25 + cp * 5 + d] * s_L[1][rr][c + d];
    }
    s_pdL[c][y] = bias + v;
  }
  for (int it = t; it < 460; it += 256) {
    int c = it / 115, y = 3 + (it - 115 * c);
    float v = 0.f;
#pragma unroll
    for (int cp = 0; cp < 5; cp++) {
      int rr = y - 2 + cp;
#pragma unroll
      for (int d = 0; d < 5; d++)
        v += s_w1[cp * 5 + d] * s_R[0][rr][c + d] + s_w1[25 + cp * 5 + d] * s_R[1][rr][c + d];
    }
    s_pdR[c][y] = bias + v;
  }
  __syncthreads();

  if (t < 252) {
    int y, x;
    if (t < 160) { y = 0; x = t; }
    else {
      int k = t - 160;
      int ri = k >> 2, xi = k & 3;
      y = 5 * (ri + 1);
      x = xi < 2 ? xi : 156 + xi;
    }
    float acc = 0.f;
    if (y == 0) {
#pragma unroll
      for (int a = 2; a < 5; a++)
#pragma unroll
        for (int bb2 = 0; bb2 < 5; bb2++)
          acc += s_kd[a * 5 + bb2] * s_pdt[a - 2][2 + x + bb2];
    } else {
#pragma unroll
      for (int a = 0; a < 5; a++) {
        int ry = y + a - 2;
#pragma unroll
        for (int bb2 = 0; bb2 < 5; bb2++) {
          int q = x + bb2 - 2;
          if (q < 0 || q >= 160) continue;
          float pdv = (q < 4) ? s_pdL[q][ry] : s_pdR[q - 156][ry];
          acc += s_kd[a * 5 + bb2] * pdv;
        }
      }
    }
#pragma unroll
    for (int dd = 0; dd < 5; dd++) {
      int ry = y + dd - 2;
      if (ry < 0 || ry >= HIM) continue;
#pragma unroll
      for (int d = 0; d < 5; d++) {
        int rx = x + d - 2;
        if (rx < 0 || rx >= WIM) continue;
        acc += s_kd[25 + dd * 5 + d] * objp[ry * WIM + rx];
      }
    }
    acc *= attn_bi;
    int q2 = i / 12, cw = i - 12 * q2;
    cpano[((size_t)b * 72 + (2 - q2) * 24 + y / 5) * 1920 + cw * WIM + x] = acc;
  }
}

// ============ kernel 5: conv2_1 on compact pano, both roll paths ============
__global__ __launch_bounds__(256) void k_c21(
    const float* __restrict__ cpano, const float* __restrict__ w21,
    const float* __restrict__ b21, float* __restrict__ y1) {
  __shared__ float s_rows[5][1920];
  int t = threadIdx.x;
  int b = blockIdx.x, oy = blockIdx.y;
  const float* pp = cpano + (size_t)b * 72 * 1920;
  for (int tt = t; tt < 2400; tt += 256) {
    int ky = tt / 480, g = tt - 480 * ky;
    *(float4*)&s_rows[ky][4 * g] = *(const float4*)&pp[(size_t)(oy + 2 * ky) * 1920 + 4 * g];
  }
  float w[25];
#pragma unroll
  for (int k = 0; k < 25; k++) w[k] = w21[k];
  float bb = b21[0];
  __syncthreads();
  for (int tt = t; tt < 538; tt += 256) {
    int p = tt / 269, ox = tt - 269 * p;
    int shift = p ? 1760 : 0;
    float acc = bb;
#pragma unroll
    for (int ky = 0; ky < 5; ky++)
#pragma unroll
      for (int kx = 0; kx < 5; kx++) {
        int X = 7 * ox + 10 * kx + shift;
        if (X >= 1920) X -= 1920;
        acc += w[ky * 5 + kx] * s_rows[ky][X];
      }
    y1[((size_t)(p * B + b) * 64 + oy) * 269 + ox] = acc;
  }
}

// ============ kernel 6: fused pools+conv2_2 (both paths) + vf softmax ============
__global__ __launch_bounds__(512) void k_tailvf(
    const float* __restrict__ y1, const float* __restrict__ w22,
    const float* __restrict__ b22, const int* __restrict__ nav_idx,
    float* __restrict__ out_vf, float* __restrict__ out_mask) {
  __shared__ float s_y2[2][21][90];
  __shared__ float s_y3[2][10][44];
  __shared__ float s_vf2[2][36];
  __shared__ float s_v[36];
  __shared__ float s_inv;
  int t = threadIdx.x;
  int b = blockIdx.x;
  int p = t >> 8, tp = t & 255;
  const float* yp = y1 + (size_t)(p * B + b) * 64 * 269;
  for (int idx = tp; idx < 21 * 89; idx += 256) {
    int py = idx / 89, px = idx - 89 * py;
    float s = 0.f;
    for (int dy = 0; dy < 3; dy++)
      for (int dx = 0; dx < 3; dx++)
        s += yp[(3 * py + dy) * 269 + 3 * px + dx];
    s_y2[p][py][px] = s * (1.0f / 9.0f);
  }
  __syncthreads();
  for (int idx = tp; idx < 10 * 43; idx += 256) {
    int qy = idx / 43, qx = idx - 43 * qy;
    float a = b22[0];
#pragma unroll
    for (int ky = 0; ky < 3; ky++)
#pragma unroll
      for (int kx = 0; kx < 3; kx++)
        a += w22[ky * 3 + kx] * s_y2[p][2 * qy + ky][2 * qx + 2 * kx];
    s_y3[p][qy][qx] = a;
  }
  __syncthreads();
  if (tp < 36) {
    int uy = tp / 12, ux = tp - 12 * uy;
    float s = 0.f;
    for (int dy = 0; dy < 3; dy++)
      for (int dx = 0; dx < 9; dx++)
        s += s_y3[p][3 * uy + dy][3 * ux + dx];
    s_vf2[p][tp] = s * (1.0f / 27.0f);
  }
  __syncthreads();
  if (t < 36) {
    int u = t / 12, x = t - 12 * u;
    float v1 = s_vf2[0][(2 - u) * 12 + x];
    float v2 = s_vf2[1][(2 - u) * 12 + (x + 1) % 12];
    s_v[t] = 0.5f * (v1 + v2) * 0.1f;
  }
  __syncthreads();
  if (t == 0) {
    float m = -1e30f;
    for (int i = 0; i < 36; i++) m = fmaxf(m, s_v[i]);
    float s = 0.f;
    for (int i = 0; i < 36; i++) { s_v[i] = expf(s_v[i] - m); s += s_v[i]; }
    s_inv = 1.0f / s;
  }
  __syncthreads();
  if (t < 36) {
    out_vf[b * 36 + t] = s_v[t] * s_inv;
    float m = 0.f;
    for (int e = 0; e < 8; e++)
      if (nav_idx[b * 8 + e] == t) m = 1.0f;
    out_mask[b * 36 + t] = m;
  }
}

// ============ kernel 7: LSTM, 512 blocks (1 unit each), f4 weight loads ============
__global__ __launch_bounds__(256) void k_lstm(
    const float* __restrict__ ctx, const float* __restrict__ vf,
    const float* __restrict__ dfa, const float* __restrict__ pre,
    const float* __restrict__ h0, const float* __restrict__ c0,
    const float* __restrict__ wih, const float* __restrict__ whh,
    const float* __restrict__ bih, const float* __restrict__ bhh,
    float* __restrict__ h1, float* __restrict__ c1) {
  __shared__ float s_cat[B][1104];   // [0,589) cat, [592,1104) h0
  __shared__ float s_g[4][16];
  int t = threadIdx.x;
  int u = blockIdx.x;
  int g = t >> 6, l = t & 63;
  for (int idx = t; idx < B * 589; idx += 256) {
    int b = idx / 589, k = idx - 589 * b;
    float v;
    if (k < 512) v = ctx[b * 512 + k];
    else if (k < 548) v = vf[b * 36 + (k - 512)];
    else if (k < 552) v = dfa[b * 4 + (k - 548)];
    else v = pre[b * 37 + (k - 552)];
    s_cat[b][k] = v;
  }
  for (int idx = t; idx < B * 512; idx += 256) {
    int b = idx >> 9, k = idx & 511;
    s_cat[b][592 + k] = h0[b * 512 + k];
  }
  __syncthreads();
  int j = (g << 9) + u;
  float acc[B];
#pragma unroll
  for (int b = 0; b < B; b++) acc[b] = 0.f;
  const float* wi = wih + (size_t)j * 589;
#pragma unroll
  for (int it = 0; it < 3; it++) {
    int c = l + 64 * it;
    if (c < 147) {
      int k = 4 * c;
      float w0 = wi[k], w1 = wi[k + 1], w2 = wi[k + 2], w3 = wi[k + 3];
#pragma unroll
      for (int b = 0; b < B; b++) {
        float4 cc = *(const float4*)&s_cat[b][k];
        acc[b] += cc.x * w0 + cc.y * w1 + cc.z * w2 + cc.w * w3;
      }
    }
  }
  if (l == 0) {
    float w = wi[588];
#pragma unroll
    for (int b = 0; b < B; b++) acc[b] += w * s_cat[b][588];
  }
  const float* wh = whh + (size_t)j * 512;
#pragma unroll
  for (int it = 0; it < 2; it++) {
    int k = 4 * (l + 64 * it);
    float4 w4 = *(const float4*)&wh[k];
#pragma unroll
    for (int b = 0; b < B; b++) {
      float4 cc = *(const float4*)&s_cat[b][592 + k];
      acc[b] += cc.x * w4.x + cc.y * w4.y + cc.z * w4.z + cc.w * w4.w;
    }
  }
#pragma unroll
  for (int off = 1; off < 64; off <<= 1)
#pragma unroll
    for (int b = 0; b < B; b++) acc[b] += __shfl_xor(acc[b], off);
  if (l == 0) {
    float bb = bih[j] + bhh[j];
#pragma unroll
    for (int b = 0; b < B; b++) s_g[g][b] = acc[b] + bb;
  }
  __syncthreads();
  if (t < 16) {
    float gi = s_g[0][t], gf = s_g[1][t], gg = s_g[2][t], go = s_g[3][t];
    float c_old = c0[t * 512 + u];
    float si = 1.0f / (1.0f + expf(-gi));
    float sf = 1.0f / (1.0f + expf(-gf));
    float so = 1.0f / (1.0f + expf(-go));
    float cn = sf * c_old + si * tanhf(gg);
    h1[t * 512 + u] = so * tanhf(cn);
    c1[t * 512 + u] = cn;
  }
}

extern "C" void kernel_launch(void* const* d_in, const int* in_sizes, int n_in,
                              void* d_out, int out_size, void* d_ws, size_t ws_size,
                              hipStream_t stream) {
  const float* depth_raw  = (const float*)d_in[0];
  const float* depth_clip = (const float*)d_in[1];
  const float* obj_feat   = (const float*)d_in[2];
  const float* nnf        = (const float*)d_in[3];
  const float* pre        = (const float*)d_in[4];
  const float* h0         = (const float*)d_in[5];
  const float* c0         = (const float*)d_in[6];
  const float* ctx        = (const float*)d_in[7];
  const int*   nav_idx    = (const int*)d_in[8];
  const float* c1w        = (const float*)d_in[9];
  const float* c1b        = (const float*)d_in[10];
  const float* fc1w       = (const float*)d_in[11];
  const float* fc1b       = (const float*)d_in[12];
  const float* fc2w       = (const float*)d_in[13];
  const float* fc2b       = (const float*)d_in[14];
  const float* dynf       = (const float*)d_in[15];
  const float* w21        = (const float*)d_in[16];
  const float* b21        = (const float*)d_in[17];
  const float* w22        = (const float*)d_in[18];
  const float* b22        = (const float*)d_in[19];
  const float* wih        = (const float*)d_in[20];
  const float* whh        = (const float*)d_in[21];
  const float* bih        = (const float*)d_in[22];
  const float* bhh        = (const float*)d_in[23];

  float* ws = (float*)d_ws;
  float* attn   = ws;
  float* dfa    = ws + 576;
  float* y1     = ws + 1792;
  float* cpano  = ws + 552704;
  float* wsC    = ws + 2764544;

  float* out = (float*)d_out;
  float* out_h1   = out;
  float* out_c1   = out + 8192;
  float* out_vf   = out + 16384;
  float* out_mask = out + 16960;

  k_head<<<B, 128, 0, stream>>>(nnf, ctx, fc1w, fc1b, fc2w, fc2b, attn, dfa);
  k_comp<<<B * NAV, 192, 0, stream>>>(c1w, c1b, dynf, attn, dfa, wsC);
  k_conv<<<B * NAV * 12, 256, 0, stream>>>(depth_raw, depth_clip, obj_feat, wsC, cpano);
  k_fix<<<B * NAV, 256, 0, stream>>>(depth_raw, depth_clip, obj_feat,
                                     c1w, c1b, attn, wsC, cpano);
  k_c21<<<dim3(B, 64), 256, 0, stream>>>(cpano, w21, b21, y1);
  k_tailvf<<<B, 512, 0, stream>>>(y1, w22, b22, nav_idx, out_vf, out_mask);
  k_lstm<<<RH, 256, 0, stream>>>(ctx, out_vf, dfa, pre, h0, c0,
                                 wih, whh, bih, bhh, out_h1, out_c1);
}